// Round 2
// baseline (1219.131 us; speedup 1.0000x reference)
//
#include <hip/hip_runtime.h>
#include <hip/hip_bf16.h>
#include <math.h>

// EncoderLayer for MI355X (gfx950).
// Key numerics: scores = q.k * sqrt(C)=8 (reference quirk) => logits ~N(0,64^2),
// near-one-hot softmax, exponentially sensitive to absolute score error.
// So q,k are computed and consumed in SPLIT bf16 (hi+lo ~= fp32):
//   - LN1 emits xl_hi/xl_lo
//   - QK gemm: 3-pass MFMA (hi*hi + hi*lo + lo*hi), epilogue re-splits to qk_hi/lo
//   - attention QK^T: 3-combo MFMA
// Everything else (V, P, O-proj, FFN) is plain bf16 MFMA (error ~0.01 << 0.1875).

typedef __hip_bfloat16 bf16_t;
typedef __bf16 bf16x8 __attribute__((ext_vector_type(8)));
typedef float f32x4 __attribute__((ext_vector_type(4)));

#define LN_EPS 1e-5f

__device__ __forceinline__ void async_copy16(const bf16_t* g, bf16_t* l) {
  __builtin_amdgcn_global_load_lds(
      (const __attribute__((address_space(1))) void*)g,
      (__attribute__((address_space(3))) void*)l,
      16 /*bytes*/, 0 /*offset*/, 0 /*aux*/);
}

__device__ __forceinline__ void split_bf16(float v, bf16_t& hi, bf16_t& lo) {
  hi = __float2bfloat16(v);
  lo = __float2bfloat16(v - __bfloat162float(hi));
}

// ---------------- LayerNorm: fp32 in -> bf16 out (one block per row of 1024)
// SPLIT: also emit lo = bf16(y - float(hi)) for fp32-accuracy downstream MFMA.
template<bool SPLIT>
__global__ __launch_bounds__(256) void ln_kernel(
    const float* __restrict__ x, const float* __restrict__ g,
    const float* __restrict__ b, bf16_t* __restrict__ out_hi,
    bf16_t* __restrict__ out_lo)
{
  const int row = blockIdx.x;
  const int tid = threadIdx.x;
  const float4 v = *(const float4*)(x + (size_t)row * 1024 + tid * 4);
  float s  = v.x + v.y + v.z + v.w;
  float ss = v.x * v.x + v.y * v.y + v.z * v.z + v.w * v.w;
  for (int off = 32; off > 0; off >>= 1) {
    s  += __shfl_down(s, off);
    ss += __shfl_down(ss, off);
  }
  __shared__ float sb[4], ssb[4];
  const int wave = tid >> 6, lane = tid & 63;
  if (lane == 0) { sb[wave] = s; ssb[wave] = ss; }
  __syncthreads();
  const float tot  = sb[0] + sb[1] + sb[2] + sb[3];
  const float tots = ssb[0] + ssb[1] + ssb[2] + ssb[3];
  const float mu   = tot * (1.0f / 1024.0f);
  const float var  = tots * (1.0f / 1024.0f) - mu * mu;
  const float rstd = rsqrtf(var + LN_EPS);
  const float4 gv = *(const float4*)(g + tid * 4);
  const float4 bv = *(const float4*)(b + tid * 4);
  float y[4] = {(v.x - mu) * rstd * gv.x + bv.x,
                (v.y - mu) * rstd * gv.y + bv.y,
                (v.z - mu) * rstd * gv.z + bv.z,
                (v.w - mu) * rstd * gv.w + bv.w};
  bf16_t hi[4] __attribute__((aligned(8)));
  bf16_t lo[4] __attribute__((aligned(8)));
  #pragma unroll
  for (int i = 0; i < 4; i++) split_bf16(y[i], hi[i], lo[i]);
  uint2 ph, pl;
  __builtin_memcpy(&ph, hi, 8);
  *(uint2*)(out_hi + (size_t)row * 1024 + tid * 4) = ph;
  if (SPLIT) {
    __builtin_memcpy(&pl, lo, 8);
    *(uint2*)(out_lo + (size_t)row * 1024 + tid * 4) = pl;
  }
}

// ---------------- Weight transpose + cast: W (KxN fp32) -> WT (NxK bf16[, lo])
// grid: (N/32, K/32), block 256 (32x8)
template<bool SPLIT>
__global__ __launch_bounds__(256) void wtrans_kernel(
    const float* __restrict__ W, bf16_t* __restrict__ WT_hi,
    bf16_t* __restrict__ WT_lo, int K, int N)
{
  __shared__ float t[32][33];
  const int n0 = blockIdx.x * 32, k0 = blockIdx.y * 32;
  const int tx = threadIdx.x & 31, ty = threadIdx.x >> 5;
  #pragma unroll
  for (int r = ty; r < 32; r += 8)
    t[r][tx] = W[(size_t)(k0 + r) * N + n0 + tx];
  __syncthreads();
  #pragma unroll
  for (int r = ty; r < 32; r += 8) {
    const float v = t[tx][r];
    bf16_t hi, lo;
    split_bf16(v, hi, lo);
    WT_hi[(size_t)(n0 + r) * K + k0 + tx] = hi;
    if (SPLIT) WT_lo[(size_t)(n0 + r) * K + k0 + tx] = lo;
  }
}

// ---------------- V transpose: v[tok][1024] (bf16) -> vT[(b*1024+n)][s]
// grid: (2048/32, 1024/32, 4), block 256 (32x8)
__global__ __launch_bounds__(256) void vtrans_kernel(
    const bf16_t* __restrict__ v, bf16_t* __restrict__ vT)
{
  __shared__ bf16_t t[32][33];
  const int s0 = blockIdx.x * 32, n0 = blockIdx.y * 32, b = blockIdx.z;
  const int tx = threadIdx.x & 31, ty = threadIdx.x >> 5;
  #pragma unroll
  for (int r = ty; r < 32; r += 8)
    t[r][tx] = v[((size_t)b * 2048 + s0 + r) * 1024 + n0 + tx];
  __syncthreads();
  #pragma unroll
  for (int r = ty; r < 32; r += 8)
    vT[((size_t)b * 1024 + n0 + r) * 2048 + s0 + tx] = t[tx][r];
}

// ---------------- GEMM: C(MxN) = A(MxK,bf16) * BT(NxK,bf16)^T [+bias][+resid][relu]
// 128x128 tile, BK=32, 4 waves (2x2), each wave 64x64 via 4x4 mfma 16x16x32.
template<bool BIAS, bool RELU, bool RESID, bool OUTBF>
__global__ __launch_bounds__(256) void gemm_kernel(
    const bf16_t* __restrict__ A, const bf16_t* __restrict__ BT,
    const float* __restrict__ bias, const float* __restrict__ resid,
    float* __restrict__ outF, bf16_t* __restrict__ outB,
    int M, int N, int K)
{
  __shared__ __align__(16) bf16_t As[128 * 32];
  __shared__ __align__(16) bf16_t Bs[128 * 32];
  const int nblk = N >> 7;
  const int bm = blockIdx.x / nblk;
  const int bn = blockIdx.x % nblk;
  const int tid  = threadIdx.x;
  const int wave = tid >> 6;
  const int lane = tid & 63;
  const int l15  = lane & 15;
  const int quad = lane >> 4;
  const int wm = wave >> 1, wn = wave & 1;

  const bf16_t* aG = A  + (size_t)(bm * 128 + wave * 32 + (lane >> 2)) * K + (lane & 3) * 8;
  const bf16_t* bG = BT + (size_t)(bn * 128 + wave * 32 + (lane >> 2)) * K + (lane & 3) * 8;
  bf16_t* aL0 = &As[(wave * 32) * 32];
  bf16_t* aL1 = &As[(wave * 32 + 16) * 32];
  bf16_t* bL0 = &Bs[(wave * 32) * 32];
  bf16_t* bL1 = &Bs[(wave * 32 + 16) * 32];

  f32x4 acc[4][4];
  #pragma unroll
  for (int i = 0; i < 4; i++)
    #pragma unroll
    for (int j = 0; j < 4; j++) acc[i][j] = (f32x4){0.f, 0.f, 0.f, 0.f};

  for (int kt = 0; kt < K; kt += 32) {
    async_copy16(aG + kt, aL0);
    async_copy16(aG + kt + (size_t)16 * K, aL1);
    async_copy16(bG + kt, bL0);
    async_copy16(bG + kt + (size_t)16 * K, bL1);
    __syncthreads();
    bf16x8 af[4], bfr[4];
    #pragma unroll
    for (int i = 0; i < 4; i++)
      af[i]  = *(const bf16x8*)&As[(wm * 64 + i * 16 + l15) * 32 + quad * 8];
    #pragma unroll
    for (int j = 0; j < 4; j++)
      bfr[j] = *(const bf16x8*)&Bs[(wn * 64 + j * 16 + l15) * 32 + quad * 8];
    #pragma unroll
    for (int i = 0; i < 4; i++)
      #pragma unroll
      for (int j = 0; j < 4; j++)
        acc[i][j] = __builtin_amdgcn_mfma_f32_16x16x32_bf16(af[i], bfr[j], acc[i][j], 0, 0, 0);
    __syncthreads();
  }

  // epilogue: C/D layout row = quad*4+reg, col = lane&15
  const int gm0 = bm * 128 + wm * 64 + quad * 4;
  const int gn0 = bn * 128 + wn * 64 + l15;
  #pragma unroll
  for (int i = 0; i < 4; i++) {
    #pragma unroll
    for (int j = 0; j < 4; j++) {
      const int gn = gn0 + j * 16;
      const float bz = BIAS ? bias[gn] : 0.0f;
      #pragma unroll
      for (int r = 0; r < 4; r++) {
        const int gm = gm0 + i * 16 + r;
        float v = acc[i][j][r] + bz;
        if (RESID) v += resid[(size_t)gm * N + gn];
        if (RELU)  v = fmaxf(v, 0.0f);
        if (OUTBF) outB[(size_t)gm * N + gn] = __float2bfloat16(v);
        else       outF[(size_t)gm * N + gn] = v;
      }
    }
  }
}

// ---------------- Split-precision GEMM for q,k:
// C = (A_hi+A_lo)(B_hi+B_lo)^T  ~=  Ah.Bh + Ah.Bl + Al.Bh  (drop lo*lo)
// Output re-split into out_hi/out_lo bf16 pair.
__global__ __launch_bounds__(256) void gemm_split_kernel(
    const bf16_t* __restrict__ Ah, const bf16_t* __restrict__ Al,
    const bf16_t* __restrict__ Bh, const bf16_t* __restrict__ Bl,
    bf16_t* __restrict__ out_hi, bf16_t* __restrict__ out_lo,
    int M, int N, int K)
{
  __shared__ __align__(16) bf16_t AsH[128 * 32];
  __shared__ __align__(16) bf16_t AsL[128 * 32];
  __shared__ __align__(16) bf16_t BsH[128 * 32];
  __shared__ __align__(16) bf16_t BsL[128 * 32];
  const int nblk = N >> 7;
  const int bm = blockIdx.x / nblk;
  const int bn = blockIdx.x % nblk;
  const int tid  = threadIdx.x;
  const int wave = tid >> 6;
  const int lane = tid & 63;
  const int l15  = lane & 15;
  const int quad = lane >> 4;
  const int wm = wave >> 1, wn = wave & 1;

  const size_t aOff = (size_t)(bm * 128 + wave * 32 + (lane >> 2)) * K + (lane & 3) * 8;
  const size_t bOff = (size_t)(bn * 128 + wave * 32 + (lane >> 2)) * K + (lane & 3) * 8;
  const int ldsOff0 = (wave * 32) * 32;
  const int ldsOff1 = (wave * 32 + 16) * 32;

  f32x4 acc[4][4];
  #pragma unroll
  for (int i = 0; i < 4; i++)
    #pragma unroll
    for (int j = 0; j < 4; j++) acc[i][j] = (f32x4){0.f, 0.f, 0.f, 0.f};

  for (int kt = 0; kt < K; kt += 32) {
    async_copy16(Ah + aOff + kt, &AsH[ldsOff0]);
    async_copy16(Ah + aOff + kt + (size_t)16 * K, &AsH[ldsOff1]);
    async_copy16(Al + aOff + kt, &AsL[ldsOff0]);
    async_copy16(Al + aOff + kt + (size_t)16 * K, &AsL[ldsOff1]);
    async_copy16(Bh + bOff + kt, &BsH[ldsOff0]);
    async_copy16(Bh + bOff + kt + (size_t)16 * K, &BsH[ldsOff1]);
    async_copy16(Bl + bOff + kt, &BsL[ldsOff0]);
    async_copy16(Bl + bOff + kt + (size_t)16 * K, &BsL[ldsOff1]);
    __syncthreads();
    bf16x8 afH[4], afL[4], bfH[4], bfL[4];
    #pragma unroll
    for (int i = 0; i < 4; i++) {
      const int o = (wm * 64 + i * 16 + l15) * 32 + quad * 8;
      afH[i] = *(const bf16x8*)&AsH[o];
      afL[i] = *(const bf16x8*)&AsL[o];
    }
    #pragma unroll
    for (int j = 0; j < 4; j++) {
      const int o = (wn * 64 + j * 16 + l15) * 32 + quad * 8;
      bfH[j] = *(const bf16x8*)&BsH[o];
      bfL[j] = *(const bf16x8*)&BsL[o];
    }
    #pragma unroll
    for (int i = 0; i < 4; i++)
      #pragma unroll
      for (int j = 0; j < 4; j++) {
        acc[i][j] = __builtin_amdgcn_mfma_f32_16x16x32_bf16(afH[i], bfH[j], acc[i][j], 0, 0, 0);
        acc[i][j] = __builtin_amdgcn_mfma_f32_16x16x32_bf16(afH[i], bfL[j], acc[i][j], 0, 0, 0);
        acc[i][j] = __builtin_amdgcn_mfma_f32_16x16x32_bf16(afL[i], bfH[j], acc[i][j], 0, 0, 0);
      }
    __syncthreads();
  }

  const int gm0 = bm * 128 + wm * 64 + quad * 4;
  const int gn0 = bn * 128 + wn * 64 + l15;
  #pragma unroll
  for (int i = 0; i < 4; i++)
    #pragma unroll
    for (int j = 0; j < 4; j++)
      #pragma unroll
      for (int r = 0; r < 4; r++) {
        const int gm = gm0 + i * 16 + r;
        const int gn = gn0 + j * 16;
        bf16_t hi, lo;
        split_bf16(acc[i][j][r], hi, lo);
        out_hi[(size_t)gm * N + gn] = hi;
        out_lo[(size_t)gm * N + gn] = lo;
      }
}

// ---------------- Flash attention with split-precision QK^T.
// grid (32 qtiles, 16 heads, 4 batch), block 256 (4 waves x 16 queries).
// qk[tok][2048]: q at col 0, k at col 1024 (hi and lo buffers).
// scores = (q.k) * 8.0  (reference multiplies by sqrt(C) -- faithful quirk)
__global__ __launch_bounds__(256) void attn_kernel(
    const bf16_t* __restrict__ qkH,  // [8192][2048]
    const bf16_t* __restrict__ qkL,  // [8192][2048]
    const bf16_t* __restrict__ vT,   // [(b*1024+n)][2048]
    bf16_t* __restrict__ o)          // [8192][1024]
{
  const int qt = blockIdx.x;
  const int h  = blockIdx.y;
  const int b  = blockIdx.z;
  const int wave = threadIdx.x >> 6;
  const int lane = threadIdx.x & 63;
  const int l15  = lane & 15;
  const int quad = lane >> 4;
  const int qrow = qt * 64 + wave * 16;

  __shared__ __align__(16) bf16_t Pl[4][16 * 32];  // per-wave P tile [q][key]

  const size_t tok0 = (size_t)b * 2048;
  const size_t qoff = (tok0 + qrow + l15) * 2048 + h * 64;
  const bf16x8 aq0H = *(const bf16x8*)(qkH + qoff + quad * 8);
  const bf16x8 aq1H = *(const bf16x8*)(qkH + qoff + 32 + quad * 8);
  const bf16x8 aq0L = *(const bf16x8*)(qkL + qoff + quad * 8);
  const bf16x8 aq1L = *(const bf16x8*)(qkL + qoff + 32 + quad * 8);

  const size_t kbase = tok0 * 2048 + 1024 + h * 64;
  const bf16_t* vbase = vT + ((size_t)b * 1024 + h * 64) * 2048;

  float mrow[4], lrow[4];
  f32x4 Of[4];
  #pragma unroll
  for (int r = 0; r < 4; r++) { mrow[r] = -3.0e38f; lrow[r] = 0.f; }
  #pragma unroll
  for (int c = 0; c < 4; c++) Of[c] = (f32x4){0.f, 0.f, 0.f, 0.f};

  bf16_t* pw = &Pl[wave][0];

  for (int kb = 0; kb < 2048; kb += 32) {
    const size_t k0 = kbase + (size_t)(kb + l15) * 2048 + quad * 8;
    const size_t k1 = k0 + (size_t)16 * 2048;
    const bf16x8 bk00H = *(const bf16x8*)(qkH + k0);
    const bf16x8 bk01H = *(const bf16x8*)(qkH + k0 + 32);
    const bf16x8 bk10H = *(const bf16x8*)(qkH + k1);
    const bf16x8 bk11H = *(const bf16x8*)(qkH + k1 + 32);
    const bf16x8 bk00L = *(const bf16x8*)(qkL + k0);
    const bf16x8 bk01L = *(const bf16x8*)(qkL + k0 + 32);
    const bf16x8 bk10L = *(const bf16x8*)(qkL + k1);
    const bf16x8 bk11L = *(const bf16x8*)(qkL + k1 + 32);

    f32x4 s0 = (f32x4){0.f, 0.f, 0.f, 0.f};
    f32x4 s1 = (f32x4){0.f, 0.f, 0.f, 0.f};
    s0 = __builtin_amdgcn_mfma_f32_16x16x32_bf16(aq0H, bk00H, s0, 0, 0, 0);
    s0 = __builtin_amdgcn_mfma_f32_16x16x32_bf16(aq1H, bk01H, s0, 0, 0, 0);
    s0 = __builtin_amdgcn_mfma_f32_16x16x32_bf16(aq0H, bk00L, s0, 0, 0, 0);
    s0 = __builtin_amdgcn_mfma_f32_16x16x32_bf16(aq1H, bk01L, s0, 0, 0, 0);
    s0 = __builtin_amdgcn_mfma_f32_16x16x32_bf16(aq0L, bk00H, s0, 0, 0, 0);
    s0 = __builtin_amdgcn_mfma_f32_16x16x32_bf16(aq1L, bk01H, s0, 0, 0, 0);
    s1 = __builtin_amdgcn_mfma_f32_16x16x32_bf16(aq0H, bk10H, s1, 0, 0, 0);
    s1 = __builtin_amdgcn_mfma_f32_16x16x32_bf16(aq1H, bk11H, s1, 0, 0, 0);
    s1 = __builtin_amdgcn_mfma_f32_16x16x32_bf16(aq0H, bk10L, s1, 0, 0, 0);
    s1 = __builtin_amdgcn_mfma_f32_16x16x32_bf16(aq1H, bk11L, s1, 0, 0, 0);
    s1 = __builtin_amdgcn_mfma_f32_16x16x32_bf16(aq0L, bk10H, s1, 0, 0, 0);
    s1 = __builtin_amdgcn_mfma_f32_16x16x32_bf16(aq1L, bk11H, s1, 0, 0, 0);

    float p0[4], p1[4], alpha[4];
    #pragma unroll
    for (int r = 0; r < 4; r++) { s0[r] *= 8.0f; s1[r] *= 8.0f; }
    #pragma unroll
    for (int r = 0; r < 4; r++) {
      float m = fmaxf(s0[r], s1[r]);
      m = fmaxf(m, __shfl_xor(m, 1));
      m = fmaxf(m, __shfl_xor(m, 2));
      m = fmaxf(m, __shfl_xor(m, 4));
      m = fmaxf(m, __shfl_xor(m, 8));
      const float mn = fmaxf(mrow[r], m);
      alpha[r] = __expf(mrow[r] - mn);
      mrow[r] = mn;
      p0[r] = __expf(s0[r] - mn);
      p1[r] = __expf(s1[r] - mn);
      float cs = p0[r] + p1[r];
      cs += __shfl_xor(cs, 1);
      cs += __shfl_xor(cs, 2);
      cs += __shfl_xor(cs, 4);
      cs += __shfl_xor(cs, 8);
      lrow[r] = lrow[r] * alpha[r] + cs;
    }
    #pragma unroll
    for (int c = 0; c < 4; c++)
      #pragma unroll
      for (int r = 0; r < 4; r++) Of[c][r] *= alpha[r];

    // P (C-layout) -> per-wave LDS -> A-layout fragment (no barrier: same wave)
    #pragma unroll
    for (int r = 0; r < 4; r++) {
      pw[(quad * 4 + r) * 32 + l15]      = __float2bfloat16(p0[r]);
      pw[(quad * 4 + r) * 32 + 16 + l15] = __float2bfloat16(p1[r]);
    }
    const bf16x8 pa = *(const bf16x8*)&pw[l15 * 32 + quad * 8];

    const bf16_t* vp = vbase + kb + quad * 8;
    #pragma unroll
    for (int c = 0; c < 4; c++) {
      const bf16x8 bv = *(const bf16x8*)(vp + (size_t)(c * 16 + l15) * 2048);
      Of[c] = __builtin_amdgcn_mfma_f32_16x16x32_bf16(pa, bv, Of[c], 0, 0, 0);
    }
  }

  bf16_t* op = o + (tok0 + qrow) * 1024 + h * 64;
  #pragma unroll
  for (int c = 0; c < 4; c++)
    #pragma unroll
    for (int r = 0; r < 4; r++) {
      const float val = Of[c][r] / lrow[r];
      op[(size_t)(quad * 4 + r) * 1024 + c * 16 + l15] = __float2bfloat16(val);
    }
}

extern "C" void kernel_launch(void* const* d_in, const int* in_sizes, int n_in,
                              void* d_out, int out_size, void* d_ws, size_t ws_size,
                              hipStream_t stream)
{
  (void)in_sizes; (void)n_in; (void)out_size; (void)ws_size;
  const float* x   = (const float*)d_in[0];
  // d_in[1] = src_mask (unused by reference)
  const float* Wk  = (const float*)d_in[2];
  const float* Wq  = (const float*)d_in[3];
  const float* Wv  = (const float*)d_in[4];
  const float* Wfc = (const float*)d_in[5];
  const float* bfc = (const float*)d_in[6];
  const float* g1  = (const float*)d_in[7];
  const float* b1  = (const float*)d_in[8];
  const float* g2  = (const float*)d_in[9];
  const float* b2  = (const float*)d_in[10];
  const float* W1  = (const float*)d_in[11];
  const float* bf1 = (const float*)d_in[12];
  const float* W2  = (const float*)d_in[13];
  const float* bf2 = (const float*)d_in[14];
  float* out = (float*)d_out;

  // Workspace layout (aliased; 172 MB total):
  //  A @0   16MB: xl_hi  -> oAtt (xl_hi dead after V gemm; attn writes oAtt)
  //  B @16  16MB: xl_lo  -> vT (dead after QK gemm) -> xl2 (vT dead after attn)
  //  C @32  64MB: qk_hi(32)+qk_lo(32) -> h1 (qk dead after attn)
  //  D @96  16MB: v
  //  E @112 32MB: x2
  //  W @144 28MB: Wqk_hi 4, Wqk_lo 4, WvT 2, WfcT 2, W1T 8, W2T 8
  char* ws = (char*)d_ws;
  bf16_t* xl_hi  = (bf16_t*)(ws + (0ull   << 20));
  bf16_t* oAtt   = xl_hi;
  bf16_t* xl_lo  = (bf16_t*)(ws + (16ull  << 20));
  bf16_t* vT     = xl_lo;
  bf16_t* xl2    = xl_lo;
  bf16_t* qk_hi  = (bf16_t*)(ws + (32ull  << 20));
  bf16_t* qk_lo  = (bf16_t*)(ws + (64ull  << 20));
  bf16_t* h1     = qk_hi;
  bf16_t* v      = (bf16_t*)(ws + (96ull  << 20));
  float*  x2     = (float*) (ws + (112ull << 20));
  bf16_t* Wqk_hi = (bf16_t*)(ws + (144ull << 20));
  bf16_t* Wqk_lo = (bf16_t*)(ws + (148ull << 20));
  bf16_t* WvT    = (bf16_t*)(ws + (152ull << 20));
  bf16_t* WfcT   = (bf16_t*)(ws + (154ull << 20));
  bf16_t* W1T    = (bf16_t*)(ws + (156ull << 20));
  bf16_t* W2T    = (bf16_t*)(ws + (164ull << 20));

  const dim3 blk(256);

  // weight transposes (input order: Wk=d_in[2], Wq=d_in[3])
  wtrans_kernel<true ><<<dim3(32, 32),  blk, 0, stream>>>(Wq,  Wqk_hi,               Wqk_lo,               1024, 1024);
  wtrans_kernel<true ><<<dim3(32, 32),  blk, 0, stream>>>(Wk,  Wqk_hi + 1024 * 1024, Wqk_lo + 1024 * 1024, 1024, 1024);
  wtrans_kernel<false><<<dim3(32, 32),  blk, 0, stream>>>(Wv,  WvT,  nullptr, 1024, 1024);
  wtrans_kernel<false><<<dim3(32, 32),  blk, 0, stream>>>(Wfc, WfcT, nullptr, 1024, 1024);
  wtrans_kernel<false><<<dim3(128, 32), blk, 0, stream>>>(W1,  W1T,  nullptr, 1024, 4096);
  wtrans_kernel<false><<<dim3(32, 128), blk, 0, stream>>>(W2,  W2T,  nullptr, 4096, 1024);

  // LN1 (split output)
  ln_kernel<true><<<8192, blk, 0, stream>>>(x, g1, b1, xl_hi, xl_lo);

  // QK split gemm: [8192,1024] x [1024,2048] -> qk_hi/lo
  gemm_split_kernel<<<64 * 16, blk, 0, stream>>>(
      xl_hi, xl_lo, Wqk_hi, Wqk_lo, qk_hi, qk_lo, 8192, 2048, 1024);

  // V gemm: plain bf16
  gemm_kernel<false, false, false, true><<<64 * 8, blk, 0, stream>>>(
      xl_hi, WvT, nullptr, nullptr, nullptr, v, 8192, 1024, 1024);

  // V transpose for PV fragment loads
  vtrans_kernel<<<dim3(64, 32, 4), blk, 0, stream>>>(v, vT);

  // flash attention -> oAtt bf16
  attn_kernel<<<dim3(32, 16, 4), blk, 0, stream>>>(qk_hi, qk_lo, vT, oAtt);

  // O projection + bfc + residual(x) -> x2 fp32
  gemm_kernel<true, false, true, false><<<64 * 8, blk, 0, stream>>>(
      oAtt, WfcT, bfc, x, x2, nullptr, 8192, 1024, 1024);

  // LN2 (plain bf16 out)
  ln_kernel<false><<<8192, blk, 0, stream>>>(x2, g2, b2, xl2, nullptr);

  // FFN1: relu(xl2 @ W1 + bf1) -> h1 bf16
  gemm_kernel<true, true, false, true><<<64 * 32, blk, 0, stream>>>(
      xl2, W1T, bf1, nullptr, nullptr, h1, 8192, 4096, 1024);

  // FFN2: h1 @ W2 + bf2 + x2 -> out fp32
  gemm_kernel<true, false, true, false><<<64 * 8, blk, 0, stream>>>(
      h1, W2T, bf2, x2, out, nullptr, 8192, 1024, 4096);
}

// Round 3
// 899.674 us; speedup vs baseline: 1.3551x; 1.3551x over previous
//
#include <hip/hip_runtime.h>
#include <hip/hip_bf16.h>
#include <math.h>

// EncoderLayer for MI355X (gfx950).
// Key numerics: scores = q.k * sqrt(C)=8 (reference quirk) => logits ~N(0,64^2),
// near-one-hot softmax, exponentially sensitive to absolute score error.
// So q,k are computed and consumed in SPLIT bf16 (hi+lo ~= fp32).
// R3: attention rewritten: block-cooperative LDS staging of K(hi/lo)/V^T via
// global_load_lds (was: per-wave scattered global fragment loads, 4x redundant),
// 64-key chunks, XOR-swizzled LDS layout (chunk ^ row&7) so fragment ds_read_b128
// is 2-way-per-bank (free) instead of 16-way conflicted.

typedef __hip_bfloat16 bf16_t;
typedef __bf16 bf16x8 __attribute__((ext_vector_type(8)));
typedef float f32x4 __attribute__((ext_vector_type(4)));

#define LN_EPS 1e-5f

__device__ __forceinline__ void async_copy16(const bf16_t* g, bf16_t* l) {
  __builtin_amdgcn_global_load_lds(
      (const __attribute__((address_space(1))) void*)g,
      (__attribute__((address_space(3))) void*)l,
      16 /*bytes*/, 0 /*offset*/, 0 /*aux*/);
}

__device__ __forceinline__ void split_bf16(float v, bf16_t& hi, bf16_t& lo) {
  hi = __float2bfloat16(v);
  lo = __float2bfloat16(v - __bfloat162float(hi));
}

// ---------------- LayerNorm: fp32 in -> bf16 out (one block per row of 1024)
template<bool SPLIT>
__global__ __launch_bounds__(256) void ln_kernel(
    const float* __restrict__ x, const float* __restrict__ g,
    const float* __restrict__ b, bf16_t* __restrict__ out_hi,
    bf16_t* __restrict__ out_lo)
{
  const int row = blockIdx.x;
  const int tid = threadIdx.x;
  const float4 v = *(const float4*)(x + (size_t)row * 1024 + tid * 4);
  float s  = v.x + v.y + v.z + v.w;
  float ss = v.x * v.x + v.y * v.y + v.z * v.z + v.w * v.w;
  for (int off = 32; off > 0; off >>= 1) {
    s  += __shfl_down(s, off);
    ss += __shfl_down(ss, off);
  }
  __shared__ float sb[4], ssb[4];
  const int wave = tid >> 6, lane = tid & 63;
  if (lane == 0) { sb[wave] = s; ssb[wave] = ss; }
  __syncthreads();
  const float tot  = sb[0] + sb[1] + sb[2] + sb[3];
  const float tots = ssb[0] + ssb[1] + ssb[2] + ssb[3];
  const float mu   = tot * (1.0f / 1024.0f);
  const float var  = tots * (1.0f / 1024.0f) - mu * mu;
  const float rstd = rsqrtf(var + LN_EPS);
  const float4 gv = *(const float4*)(g + tid * 4);
  const float4 bv = *(const float4*)(b + tid * 4);
  float y[4] = {(v.x - mu) * rstd * gv.x + bv.x,
                (v.y - mu) * rstd * gv.y + bv.y,
                (v.z - mu) * rstd * gv.z + bv.z,
                (v.w - mu) * rstd * gv.w + bv.w};
  bf16_t hi[4] __attribute__((aligned(8)));
  bf16_t lo[4] __attribute__((aligned(8)));
  #pragma unroll
  for (int i = 0; i < 4; i++) split_bf16(y[i], hi[i], lo[i]);
  uint2 ph, pl;
  __builtin_memcpy(&ph, hi, 8);
  *(uint2*)(out_hi + (size_t)row * 1024 + tid * 4) = ph;
  if (SPLIT) {
    __builtin_memcpy(&pl, lo, 8);
    *(uint2*)(out_lo + (size_t)row * 1024 + tid * 4) = pl;
  }
}

// ---------------- Weight transpose + cast: W (KxN fp32) -> WT (NxK bf16[, lo])
template<bool SPLIT>
__global__ __launch_bounds__(256) void wtrans_kernel(
    const float* __restrict__ W, bf16_t* __restrict__ WT_hi,
    bf16_t* __restrict__ WT_lo, int K, int N)
{
  __shared__ float t[32][33];
  const int n0 = blockIdx.x * 32, k0 = blockIdx.y * 32;
  const int tx = threadIdx.x & 31, ty = threadIdx.x >> 5;
  #pragma unroll
  for (int r = ty; r < 32; r += 8)
    t[r][tx] = W[(size_t)(k0 + r) * N + n0 + tx];
  __syncthreads();
  #pragma unroll
  for (int r = ty; r < 32; r += 8) {
    const float v = t[tx][r];
    bf16_t hi, lo;
    split_bf16(v, hi, lo);
    WT_hi[(size_t)(n0 + r) * K + k0 + tx] = hi;
    if (SPLIT) WT_lo[(size_t)(n0 + r) * K + k0 + tx] = lo;
  }
}

// ---------------- V transpose: v[tok][1024] (bf16) -> vT[(b*1024+n)][s]
__global__ __launch_bounds__(256) void vtrans_kernel(
    const bf16_t* __restrict__ v, bf16_t* __restrict__ vT)
{
  __shared__ bf16_t t[32][33];
  const int s0 = blockIdx.x * 32, n0 = blockIdx.y * 32, b = blockIdx.z;
  const int tx = threadIdx.x & 31, ty = threadIdx.x >> 5;
  #pragma unroll
  for (int r = ty; r < 32; r += 8)
    t[r][tx] = v[((size_t)b * 2048 + s0 + r) * 1024 + n0 + tx];
  __syncthreads();
  #pragma unroll
  for (int r = ty; r < 32; r += 8)
    vT[((size_t)b * 1024 + n0 + r) * 2048 + s0 + tx] = t[tx][r];
}

// ---------------- GEMM: C(MxN) = A(MxK,bf16) * BT(NxK,bf16)^T [+bias][+resid][relu]
template<bool BIAS, bool RELU, bool RESID, bool OUTBF>
__global__ __launch_bounds__(256) void gemm_kernel(
    const bf16_t* __restrict__ A, const bf16_t* __restrict__ BT,
    const float* __restrict__ bias, const float* __restrict__ resid,
    float* __restrict__ outF, bf16_t* __restrict__ outB,
    int M, int N, int K)
{
  __shared__ __align__(16) bf16_t As[128 * 32];
  __shared__ __align__(16) bf16_t Bs[128 * 32];
  const int nblk = N >> 7;
  const int bm = blockIdx.x / nblk;
  const int bn = blockIdx.x % nblk;
  const int tid  = threadIdx.x;
  const int wave = tid >> 6;
  const int lane = tid & 63;
  const int l15  = lane & 15;
  const int quad = lane >> 4;
  const int wm = wave >> 1, wn = wave & 1;

  const bf16_t* aG = A  + (size_t)(bm * 128 + wave * 32 + (lane >> 2)) * K + (lane & 3) * 8;
  const bf16_t* bG = BT + (size_t)(bn * 128 + wave * 32 + (lane >> 2)) * K + (lane & 3) * 8;
  bf16_t* aL0 = &As[(wave * 32) * 32];
  bf16_t* aL1 = &As[(wave * 32 + 16) * 32];
  bf16_t* bL0 = &Bs[(wave * 32) * 32];
  bf16_t* bL1 = &Bs[(wave * 32 + 16) * 32];

  f32x4 acc[4][4];
  #pragma unroll
  for (int i = 0; i < 4; i++)
    #pragma unroll
    for (int j = 0; j < 4; j++) acc[i][j] = (f32x4){0.f, 0.f, 0.f, 0.f};

  for (int kt = 0; kt < K; kt += 32) {
    async_copy16(aG + kt, aL0);
    async_copy16(aG + kt + (size_t)16 * K, aL1);
    async_copy16(bG + kt, bL0);
    async_copy16(bG + kt + (size_t)16 * K, bL1);
    __syncthreads();
    bf16x8 af[4], bfr[4];
    #pragma unroll
    for (int i = 0; i < 4; i++)
      af[i]  = *(const bf16x8*)&As[(wm * 64 + i * 16 + l15) * 32 + quad * 8];
    #pragma unroll
    for (int j = 0; j < 4; j++)
      bfr[j] = *(const bf16x8*)&Bs[(wn * 64 + j * 16 + l15) * 32 + quad * 8];
    #pragma unroll
    for (int i = 0; i < 4; i++)
      #pragma unroll
      for (int j = 0; j < 4; j++)
        acc[i][j] = __builtin_amdgcn_mfma_f32_16x16x32_bf16(af[i], bfr[j], acc[i][j], 0, 0, 0);
    __syncthreads();
  }

  const int gm0 = bm * 128 + wm * 64 + quad * 4;
  const int gn0 = bn * 128 + wn * 64 + l15;
  #pragma unroll
  for (int i = 0; i < 4; i++) {
    #pragma unroll
    for (int j = 0; j < 4; j++) {
      const int gn = gn0 + j * 16;
      const float bz = BIAS ? bias[gn] : 0.0f;
      #pragma unroll
      for (int r = 0; r < 4; r++) {
        const int gm = gm0 + i * 16 + r;
        float v = acc[i][j][r] + bz;
        if (RESID) v += resid[(size_t)gm * N + gn];
        if (RELU)  v = fmaxf(v, 0.0f);
        if (OUTBF) outB[(size_t)gm * N + gn] = __float2bfloat16(v);
        else       outF[(size_t)gm * N + gn] = v;
      }
    }
  }
}

// ---------------- Split-precision GEMM for q,k
__global__ __launch_bounds__(256) void gemm_split_kernel(
    const bf16_t* __restrict__ Ah, const bf16_t* __restrict__ Al,
    const bf16_t* __restrict__ Bh, const bf16_t* __restrict__ Bl,
    bf16_t* __restrict__ out_hi, bf16_t* __restrict__ out_lo,
    int M, int N, int K)
{
  __shared__ __align__(16) bf16_t AsH[128 * 32];
  __shared__ __align__(16) bf16_t AsL[128 * 32];
  __shared__ __align__(16) bf16_t BsH[128 * 32];
  __shared__ __align__(16) bf16_t BsL[128 * 32];
  const int nblk = N >> 7;
  const int bm = blockIdx.x / nblk;
  const int bn = blockIdx.x % nblk;
  const int tid  = threadIdx.x;
  const int wave = tid >> 6;
  const int lane = tid & 63;
  const int l15  = lane & 15;
  const int quad = lane >> 4;
  const int wm = wave >> 1, wn = wave & 1;

  const size_t aOff = (size_t)(bm * 128 + wave * 32 + (lane >> 2)) * K + (lane & 3) * 8;
  const size_t bOff = (size_t)(bn * 128 + wave * 32 + (lane >> 2)) * K + (lane & 3) * 8;
  const int ldsOff0 = (wave * 32) * 32;
  const int ldsOff1 = (wave * 32 + 16) * 32;

  f32x4 acc[4][4];
  #pragma unroll
  for (int i = 0; i < 4; i++)
    #pragma unroll
    for (int j = 0; j < 4; j++) acc[i][j] = (f32x4){0.f, 0.f, 0.f, 0.f};

  for (int kt = 0; kt < K; kt += 32) {
    async_copy16(Ah + aOff + kt, &AsH[ldsOff0]);
    async_copy16(Ah + aOff + kt + (size_t)16 * K, &AsH[ldsOff1]);
    async_copy16(Al + aOff + kt, &AsL[ldsOff0]);
    async_copy16(Al + aOff + kt + (size_t)16 * K, &AsL[ldsOff1]);
    async_copy16(Bh + bOff + kt, &BsH[ldsOff0]);
    async_copy16(Bh + bOff + kt + (size_t)16 * K, &BsH[ldsOff1]);
    async_copy16(Bl + bOff + kt, &BsL[ldsOff0]);
    async_copy16(Bl + bOff + kt + (size_t)16 * K, &BsL[ldsOff1]);
    __syncthreads();
    bf16x8 afH[4], afL[4], bfH[4], bfL[4];
    #pragma unroll
    for (int i = 0; i < 4; i++) {
      const int o = (wm * 64 + i * 16 + l15) * 32 + quad * 8;
      afH[i] = *(const bf16x8*)&AsH[o];
      afL[i] = *(const bf16x8*)&AsL[o];
    }
    #pragma unroll
    for (int j = 0; j < 4; j++) {
      const int o = (wn * 64 + j * 16 + l15) * 32 + quad * 8;
      bfH[j] = *(const bf16x8*)&BsH[o];
      bfL[j] = *(const bf16x8*)&BsL[o];
    }
    #pragma unroll
    for (int i = 0; i < 4; i++)
      #pragma unroll
      for (int j = 0; j < 4; j++) {
        acc[i][j] = __builtin_amdgcn_mfma_f32_16x16x32_bf16(afH[i], bfH[j], acc[i][j], 0, 0, 0);
        acc[i][j] = __builtin_amdgcn_mfma_f32_16x16x32_bf16(afH[i], bfL[j], acc[i][j], 0, 0, 0);
        acc[i][j] = __builtin_amdgcn_mfma_f32_16x16x32_bf16(afL[i], bfH[j], acc[i][j], 0, 0, 0);
      }
    __syncthreads();
  }

  const int gm0 = bm * 128 + wm * 64 + quad * 4;
  const int gn0 = bn * 128 + wn * 64 + l15;
  #pragma unroll
  for (int i = 0; i < 4; i++)
    #pragma unroll
    for (int j = 0; j < 4; j++)
      #pragma unroll
      for (int r = 0; r < 4; r++) {
        const int gm = gm0 + i * 16 + r;
        const int gn = gn0 + j * 16;
        bf16_t hi, lo;
        split_bf16(acc[i][j][r], hi, lo);
        out_hi[(size_t)gm * N + gn] = hi;
        out_lo[(size_t)gm * N + gn] = lo;
      }
}

// ---------------- Flash attention v3: block-cooperative LDS staging, 64-key
// chunks, XOR-swizzled LDS (slot = chunk ^ (row&7); 2 lanes/bank on reads).
// grid (32 qtiles, 16 heads, 4 batch), block 256 (4 waves x 16 queries).
__global__ __launch_bounds__(256) void attn_kernel(
    const bf16_t* __restrict__ qkH,  // [8192][2048] q at col 0, k at col 1024
    const bf16_t* __restrict__ qkL,
    const bf16_t* __restrict__ vT,   // [(b*1024+n)][2048]
    bf16_t* __restrict__ o)          // [8192][1024]
{
  const int qt = blockIdx.x;
  const int h  = blockIdx.y;
  const int b  = blockIdx.z;
  const int wave = threadIdx.x >> 6;
  const int lane = threadIdx.x & 63;
  const int l15  = lane & 15;
  const int quad = lane >> 4;
  const int qrow = qt * 64 + wave * 16;
  const int sw   = l15 & 7;

  __shared__ __align__(16) bf16_t KhL[64 * 64];
  __shared__ __align__(16) bf16_t KlL[64 * 64];
  __shared__ __align__(16) bf16_t VtL[64 * 64];   // [dim][key]
  __shared__ __align__(16) bf16_t Pl[4][16 * 64]; // per-wave P [q][key]

  const size_t tok0 = (size_t)b * 2048;
  const size_t qoff = (tok0 + qrow + l15) * 2048 + h * 64;
  const bf16x8 aq0H = *(const bf16x8*)(qkH + qoff + quad * 8);
  const bf16x8 aq1H = *(const bf16x8*)(qkH + qoff + 32 + quad * 8);
  const bf16x8 aq0L = *(const bf16x8*)(qkL + qoff + quad * 8);
  const bf16x8 aq1L = *(const bf16x8*)(qkL + qoff + 32 + quad * 8);

  const int   kOff  = 1024 + h * 64;              // col of k in qk row
  const size_t vRow0 = (size_t)b * 1024 + h * 64; // first vT row for this head

  // staging lane mapping: lane i -> row (i>>3), slot (i&7) holds global
  // chunk (i&7)^(i>>3)  => logical chunk c of row r lives at slot c^(r&7)
  const int rsub = lane >> 3;
  const int csw  = (lane & 7) ^ rsub;

  float Mrow[4], lrow[4];
  f32x4 Of[4];
  #pragma unroll
  for (int r = 0; r < 4; r++) { Mrow[r] = -3.0e38f; lrow[r] = 0.f; }
  #pragma unroll
  for (int c = 0; c < 4; c++) Of[c] = (f32x4){0.f, 0.f, 0.f, 0.f};

  bf16_t* pw = &Pl[wave][0];
  const float C1 = 11.541560327111707f; // 8 * log2(e)

  for (int kb = 0; kb < 2048; kb += 64) {
    // ---- stage K(hi/lo) and V^T chunk: each wave covers 16 rows
    #pragma unroll
    for (int j = 0; j < 2; j++) {
      const int row0 = wave * 16 + j * 8;
      const size_t krow = tok0 + kb + row0 + rsub;
      async_copy16(qkH + krow * 2048 + kOff + csw * 8, &KhL[row0 * 64]);
      async_copy16(qkL + krow * 2048 + kOff + csw * 8, &KlL[row0 * 64]);
      async_copy16(vT + (vRow0 + row0 + rsub) * 2048 + kb + csw * 8, &VtL[row0 * 64]);
    }
    __syncthreads();

    // ---- QK^T: 4 key tiles of 16
    f32x4 s[4];
    #pragma unroll
    for (int t = 0; t < 4; t++) {
      const int base = (t * 16 + l15) * 64;
      const bf16x8 bh0 = *(const bf16x8*)&KhL[base + ((quad) ^ sw) * 8];
      const bf16x8 bh1 = *(const bf16x8*)&KhL[base + ((4 + quad) ^ sw) * 8];
      const bf16x8 bl0 = *(const bf16x8*)&KlL[base + ((quad) ^ sw) * 8];
      const bf16x8 bl1 = *(const bf16x8*)&KlL[base + ((4 + quad) ^ sw) * 8];
      f32x4 acc = (f32x4){0.f, 0.f, 0.f, 0.f};
      acc = __builtin_amdgcn_mfma_f32_16x16x32_bf16(aq0H, bh0, acc, 0, 0, 0);
      acc = __builtin_amdgcn_mfma_f32_16x16x32_bf16(aq1H, bh1, acc, 0, 0, 0);
      acc = __builtin_amdgcn_mfma_f32_16x16x32_bf16(aq0H, bl0, acc, 0, 0, 0);
      acc = __builtin_amdgcn_mfma_f32_16x16x32_bf16(aq1H, bl1, acc, 0, 0, 0);
      acc = __builtin_amdgcn_mfma_f32_16x16x32_bf16(aq0L, bh0, acc, 0, 0, 0);
      acc = __builtin_amdgcn_mfma_f32_16x16x32_bf16(aq1L, bh1, acc, 0, 0, 0);
      s[t] = acc;
    }

    // ---- online softmax (log2-units: M = score*log2e; score = 8*s)
    float alpha[4];
    #pragma unroll
    for (int r = 0; r < 4; r++) {
      float m = fmaxf(fmaxf(s[0][r], s[1][r]), fmaxf(s[2][r], s[3][r]));
      m = fmaxf(m, __shfl_xor(m, 1));
      m = fmaxf(m, __shfl_xor(m, 2));
      m = fmaxf(m, __shfl_xor(m, 4));
      m = fmaxf(m, __shfl_xor(m, 8));
      const float Mnew = fmaxf(Mrow[r], m * C1);
      alpha[r] = exp2f(Mrow[r] - Mnew);
      Mrow[r] = Mnew;
      float ps[4];
      #pragma unroll
      for (int t = 0; t < 4; t++) ps[t] = exp2f(fmaf(s[t][r], C1, -Mnew));
      float cs = (ps[0] + ps[1]) + (ps[2] + ps[3]);
      cs += __shfl_xor(cs, 1);
      cs += __shfl_xor(cs, 2);
      cs += __shfl_xor(cs, 4);
      cs += __shfl_xor(cs, 8);
      lrow[r] = fmaf(lrow[r], alpha[r], cs);
      // write P (swizzled): key t*16+l15, row R=quad*4+r
      const int R = quad * 4 + r;
      #pragma unroll
      for (int t = 0; t < 4; t++)
        pw[R * 64 + (((t * 2 + (l15 >> 3)) ^ (R & 7)) * 8) + (l15 & 7)] =
            __float2bfloat16(ps[t]);
    }
    #pragma unroll
    for (int c = 0; c < 4; c++)
      #pragma unroll
      for (int r = 0; r < 4; r++) Of[c][r] *= alpha[r];

    // ---- PV (P round-trip is same-wave: no barrier needed)
    const bf16x8 pa0 = *(const bf16x8*)&pw[l15 * 64 + ((quad) ^ sw) * 8];
    const bf16x8 pa1 = *(const bf16x8*)&pw[l15 * 64 + ((4 + quad) ^ sw) * 8];
    #pragma unroll
    for (int c = 0; c < 4; c++) {
      const int vb = (c * 16 + l15) * 64;
      const bf16x8 bv0 = *(const bf16x8*)&VtL[vb + ((quad) ^ sw) * 8];
      const bf16x8 bv1 = *(const bf16x8*)&VtL[vb + ((4 + quad) ^ sw) * 8];
      Of[c] = __builtin_amdgcn_mfma_f32_16x16x32_bf16(pa0, bv0, Of[c], 0, 0, 0);
      Of[c] = __builtin_amdgcn_mfma_f32_16x16x32_bf16(pa1, bv1, Of[c], 0, 0, 0);
    }
    __syncthreads();
  }

  bf16_t* op = o + (tok0 + qrow) * 1024 + h * 64;
  #pragma unroll
  for (int c = 0; c < 4; c++)
    #pragma unroll
    for (int r = 0; r < 4; r++) {
      const float val = Of[c][r] / lrow[r];
      op[(size_t)(quad * 4 + r) * 1024 + c * 16 + l15] = __float2bfloat16(val);
    }
}

extern "C" void kernel_launch(void* const* d_in, const int* in_sizes, int n_in,
                              void* d_out, int out_size, void* d_ws, size_t ws_size,
                              hipStream_t stream)
{
  (void)in_sizes; (void)n_in; (void)out_size; (void)ws_size;
  const float* x   = (const float*)d_in[0];
  const float* Wk  = (const float*)d_in[2];
  const float* Wq  = (const float*)d_in[3];
  const float* Wv  = (const float*)d_in[4];
  const float* Wfc = (const float*)d_in[5];
  const float* bfc = (const float*)d_in[6];
  const float* g1  = (const float*)d_in[7];
  const float* b1  = (const float*)d_in[8];
  const float* g2  = (const float*)d_in[9];
  const float* b2  = (const float*)d_in[10];
  const float* W1  = (const float*)d_in[11];
  const float* bf1 = (const float*)d_in[12];
  const float* W2  = (const float*)d_in[13];
  const float* bf2 = (const float*)d_in[14];
  float* out = (float*)d_out;

  char* ws = (char*)d_ws;
  bf16_t* xl_hi  = (bf16_t*)(ws + (0ull   << 20));
  bf16_t* oAtt   = xl_hi;
  bf16_t* xl_lo  = (bf16_t*)(ws + (16ull  << 20));
  bf16_t* vT     = xl_lo;
  bf16_t* xl2    = xl_lo;
  bf16_t* qk_hi  = (bf16_t*)(ws + (32ull  << 20));
  bf16_t* qk_lo  = (bf16_t*)(ws + (64ull  << 20));
  bf16_t* h1     = qk_hi;
  bf16_t* v      = (bf16_t*)(ws + (96ull  << 20));
  float*  x2     = (float*) (ws + (112ull << 20));
  bf16_t* Wqk_hi = (bf16_t*)(ws + (144ull << 20));
  bf16_t* Wqk_lo = (bf16_t*)(ws + (148ull << 20));
  bf16_t* WvT    = (bf16_t*)(ws + (152ull << 20));
  bf16_t* WfcT   = (bf16_t*)(ws + (154ull << 20));
  bf16_t* W1T    = (bf16_t*)(ws + (156ull << 20));
  bf16_t* W2T    = (bf16_t*)(ws + (164ull << 20));

  const dim3 blk(256);

  wtrans_kernel<true ><<<dim3(32, 32),  blk, 0, stream>>>(Wq,  Wqk_hi,               Wqk_lo,               1024, 1024);
  wtrans_kernel<true ><<<dim3(32, 32),  blk, 0, stream>>>(Wk,  Wqk_hi + 1024 * 1024, Wqk_lo + 1024 * 1024, 1024, 1024);
  wtrans_kernel<false><<<dim3(32, 32),  blk, 0, stream>>>(Wv,  WvT,  nullptr, 1024, 1024);
  wtrans_kernel<false><<<dim3(32, 32),  blk, 0, stream>>>(Wfc, WfcT, nullptr, 1024, 1024);
  wtrans_kernel<false><<<dim3(128, 32), blk, 0, stream>>>(W1,  W1T,  nullptr, 1024, 4096);
  wtrans_kernel<false><<<dim3(32, 128), blk, 0, stream>>>(W2,  W2T,  nullptr, 4096, 1024);

  ln_kernel<true><<<8192, blk, 0, stream>>>(x, g1, b1, xl_hi, xl_lo);

  gemm_split_kernel<<<64 * 16, blk, 0, stream>>>(
      xl_hi, xl_lo, Wqk_hi, Wqk_lo, qk_hi, qk_lo, 8192, 2048, 1024);

  gemm_kernel<false, false, false, true><<<64 * 8, blk, 0, stream>>>(
      xl_hi, WvT, nullptr, nullptr, nullptr, v, 8192, 1024, 1024);

  vtrans_kernel<<<dim3(64, 32, 4), blk, 0, stream>>>(v, vT);

  attn_kernel<<<dim3(32, 16, 4), blk, 0, stream>>>(qk_hi, qk_lo, vT, oAtt);

  gemm_kernel<true, false, true, false><<<64 * 8, blk, 0, stream>>>(
      oAtt, WfcT, bfc, x, x2, nullptr, 8192, 1024, 1024);

  ln_kernel<false><<<8192, blk, 0, stream>>>(x2, g2, b2, xl2, nullptr);

  gemm_kernel<true, true, false, true><<<64 * 32, blk, 0, stream>>>(
      xl2, W1T, bf1, nullptr, nullptr, h1, 8192, 4096, 1024);

  gemm_kernel<true, false, true, false><<<64 * 8, blk, 0, stream>>>(
      h1, W2T, bf2, x2, out, nullptr, 8192, 1024, 4096);
}

// Round 4
// 788.271 us; speedup vs baseline: 1.5466x; 1.1413x over previous
//
#include <hip/hip_runtime.h>
#include <hip/hip_bf16.h>
#include <math.h>

// EncoderLayer for MI355X (gfx950).
// Numerics: scores = q.k * sqrt(C)=8 (reference quirk) => logits ~N(0,64^2),
// near-one-hot softmax => q,k computed/consumed in SPLIT bf16 (hi+lo ~= fp32).
// R4: attention = TWO-PASS softmax with fixed per-row M:
//   pass1: hi*hi-only scores, register max over all keys, one shfl chain; M=est+4
//   pass2: acc init = -M (free), p=exp2(s), no alpha/rescale/per-chunk chains.
//   8*log2e folded into q in the QK-gemm epilogue (fp32, before split).
// Uniform-M argument: fixed M scales all p uniformly; l-division cancels it,
// so an overestimated M is exactly correct (only avoid overflow; fp can't).

typedef __hip_bfloat16 bf16_t;
typedef __bf16 bf16x8 __attribute__((ext_vector_type(8)));
typedef float f32x4 __attribute__((ext_vector_type(4)));

#define LN_EPS 1e-5f
#define QSCALE 11.541560327111707f  // 8 * log2(e)

__device__ __forceinline__ void async_copy16(const bf16_t* g, bf16_t* l) {
  __builtin_amdgcn_global_load_lds(
      (const __attribute__((address_space(1))) void*)g,
      (__attribute__((address_space(3))) void*)l,
      16 /*bytes*/, 0 /*offset*/, 0 /*aux*/);
}

__device__ __forceinline__ void split_bf16(float v, bf16_t& hi, bf16_t& lo) {
  hi = __float2bfloat16(v);
  lo = __float2bfloat16(v - __bfloat162float(hi));
}

// ---------------- LayerNorm: fp32 in -> bf16 out (one block per row of 1024)
template<bool SPLIT>
__global__ __launch_bounds__(256) void ln_kernel(
    const float* __restrict__ x, const float* __restrict__ g,
    const float* __restrict__ b, bf16_t* __restrict__ out_hi,
    bf16_t* __restrict__ out_lo)
{
  const int row = blockIdx.x;
  const int tid = threadIdx.x;
  const float4 v = *(const float4*)(x + (size_t)row * 1024 + tid * 4);
  float s  = v.x + v.y + v.z + v.w;
  float ss = v.x * v.x + v.y * v.y + v.z * v.z + v.w * v.w;
  for (int off = 32; off > 0; off >>= 1) {
    s  += __shfl_down(s, off);
    ss += __shfl_down(ss, off);
  }
  __shared__ float sb[4], ssb[4];
  const int wave = tid >> 6, lane = tid & 63;
  if (lane == 0) { sb[wave] = s; ssb[wave] = ss; }
  __syncthreads();
  const float tot  = sb[0] + sb[1] + sb[2] + sb[3];
  const float tots = ssb[0] + ssb[1] + ssb[2] + ssb[3];
  const float mu   = tot * (1.0f / 1024.0f);
  const float var  = tots * (1.0f / 1024.0f) - mu * mu;
  const float rstd = rsqrtf(var + LN_EPS);
  const float4 gv = *(const float4*)(g + tid * 4);
  const float4 bv = *(const float4*)(b + tid * 4);
  float y[4] = {(v.x - mu) * rstd * gv.x + bv.x,
                (v.y - mu) * rstd * gv.y + bv.y,
                (v.z - mu) * rstd * gv.z + bv.z,
                (v.w - mu) * rstd * gv.w + bv.w};
  bf16_t hi[4] __attribute__((aligned(8)));
  bf16_t lo[4] __attribute__((aligned(8)));
  #pragma unroll
  for (int i = 0; i < 4; i++) split_bf16(y[i], hi[i], lo[i]);
  uint2 ph, pl;
  __builtin_memcpy(&ph, hi, 8);
  *(uint2*)(out_hi + (size_t)row * 1024 + tid * 4) = ph;
  if (SPLIT) {
    __builtin_memcpy(&pl, lo, 8);
    *(uint2*)(out_lo + (size_t)row * 1024 + tid * 4) = pl;
  }
}

// ---------------- Weight transpose + cast: W (KxN fp32) -> WT (NxK bf16[, lo])
template<bool SPLIT>
__global__ __launch_bounds__(256) void wtrans_kernel(
    const float* __restrict__ W, bf16_t* __restrict__ WT_hi,
    bf16_t* __restrict__ WT_lo, int K, int N)
{
  __shared__ float t[32][33];
  const int n0 = blockIdx.x * 32, k0 = blockIdx.y * 32;
  const int tx = threadIdx.x & 31, ty = threadIdx.x >> 5;
  #pragma unroll
  for (int r = ty; r < 32; r += 8)
    t[r][tx] = W[(size_t)(k0 + r) * N + n0 + tx];
  __syncthreads();
  #pragma unroll
  for (int r = ty; r < 32; r += 8) {
    const float v = t[tx][r];
    bf16_t hi, lo;
    split_bf16(v, hi, lo);
    WT_hi[(size_t)(n0 + r) * K + k0 + tx] = hi;
    if (SPLIT) WT_lo[(size_t)(n0 + r) * K + k0 + tx] = lo;
  }
}

// ---------------- V transpose: v[tok][1024] (bf16) -> vT[(b*1024+n)][s]
__global__ __launch_bounds__(256) void vtrans_kernel(
    const bf16_t* __restrict__ v, bf16_t* __restrict__ vT)
{
  __shared__ bf16_t t[32][33];
  const int s0 = blockIdx.x * 32, n0 = blockIdx.y * 32, b = blockIdx.z;
  const int tx = threadIdx.x & 31, ty = threadIdx.x >> 5;
  #pragma unroll
  for (int r = ty; r < 32; r += 8)
    t[r][tx] = v[((size_t)b * 2048 + s0 + r) * 1024 + n0 + tx];
  __syncthreads();
  #pragma unroll
  for (int r = ty; r < 32; r += 8)
    vT[((size_t)b * 1024 + n0 + r) * 2048 + s0 + tx] = t[tx][r];
}

// ---------------- GEMM: C(MxN) = A(MxK,bf16) * BT(NxK,bf16)^T [+bias][+resid][relu]
template<bool BIAS, bool RELU, bool RESID, bool OUTBF>
__global__ __launch_bounds__(256) void gemm_kernel(
    const bf16_t* __restrict__ A, const bf16_t* __restrict__ BT,
    const float* __restrict__ bias, const float* __restrict__ resid,
    float* __restrict__ outF, bf16_t* __restrict__ outB,
    int M, int N, int K)
{
  __shared__ __align__(16) bf16_t As[128 * 32];
  __shared__ __align__(16) bf16_t Bs[128 * 32];
  const int nblk = N >> 7;
  const int bm = blockIdx.x / nblk;
  const int bn = blockIdx.x % nblk;
  const int tid  = threadIdx.x;
  const int wave = tid >> 6;
  const int lane = tid & 63;
  const int l15  = lane & 15;
  const int quad = lane >> 4;
  const int wm = wave >> 1, wn = wave & 1;

  const bf16_t* aG = A  + (size_t)(bm * 128 + wave * 32 + (lane >> 2)) * K + (lane & 3) * 8;
  const bf16_t* bG = BT + (size_t)(bn * 128 + wave * 32 + (lane >> 2)) * K + (lane & 3) * 8;
  bf16_t* aL0 = &As[(wave * 32) * 32];
  bf16_t* aL1 = &As[(wave * 32 + 16) * 32];
  bf16_t* bL0 = &Bs[(wave * 32) * 32];
  bf16_t* bL1 = &Bs[(wave * 32 + 16) * 32];

  f32x4 acc[4][4];
  #pragma unroll
  for (int i = 0; i < 4; i++)
    #pragma unroll
    for (int j = 0; j < 4; j++) acc[i][j] = (f32x4){0.f, 0.f, 0.f, 0.f};

  for (int kt = 0; kt < K; kt += 32) {
    async_copy16(aG + kt, aL0);
    async_copy16(aG + kt + (size_t)16 * K, aL1);
    async_copy16(bG + kt, bL0);
    async_copy16(bG + kt + (size_t)16 * K, bL1);
    __syncthreads();
    bf16x8 af[4], bfr[4];
    #pragma unroll
    for (int i = 0; i < 4; i++)
      af[i]  = *(const bf16x8*)&As[(wm * 64 + i * 16 + l15) * 32 + quad * 8];
    #pragma unroll
    for (int j = 0; j < 4; j++)
      bfr[j] = *(const bf16x8*)&Bs[(wn * 64 + j * 16 + l15) * 32 + quad * 8];
    #pragma unroll
    for (int i = 0; i < 4; i++)
      #pragma unroll
      for (int j = 0; j < 4; j++)
        acc[i][j] = __builtin_amdgcn_mfma_f32_16x16x32_bf16(af[i], bfr[j], acc[i][j], 0, 0, 0);
    __syncthreads();
  }

  const int gm0 = bm * 128 + wm * 64 + quad * 4;
  const int gn0 = bn * 128 + wn * 64 + l15;
  #pragma unroll
  for (int i = 0; i < 4; i++) {
    #pragma unroll
    for (int j = 0; j < 4; j++) {
      const int gn = gn0 + j * 16;
      const float bz = BIAS ? bias[gn] : 0.0f;
      #pragma unroll
      for (int r = 0; r < 4; r++) {
        const int gm = gm0 + i * 16 + r;
        float v = acc[i][j][r] + bz;
        if (RESID) v += resid[(size_t)gm * N + gn];
        if (RELU)  v = fmaxf(v, 0.0f);
        if (OUTBF) outB[(size_t)gm * N + gn] = __float2bfloat16(v);
        else       outF[(size_t)gm * N + gn] = v;
      }
    }
  }
}

// ---------------- Split-precision GEMM for q,k.
// Epilogue scales q columns (gn<1024) by 8*log2e in fp32 BEFORE re-splitting,
// so attention scores come out of QK^T directly in log2 units.
__global__ __launch_bounds__(256) void gemm_split_kernel(
    const bf16_t* __restrict__ Ah, const bf16_t* __restrict__ Al,
    const bf16_t* __restrict__ Bh, const bf16_t* __restrict__ Bl,
    bf16_t* __restrict__ out_hi, bf16_t* __restrict__ out_lo,
    int M, int N, int K)
{
  __shared__ __align__(16) bf16_t AsH[128 * 32];
  __shared__ __align__(16) bf16_t AsL[128 * 32];
  __shared__ __align__(16) bf16_t BsH[128 * 32];
  __shared__ __align__(16) bf16_t BsL[128 * 32];
  const int nblk = N >> 7;
  const int bm = blockIdx.x / nblk;
  const int bn = blockIdx.x % nblk;
  const int tid  = threadIdx.x;
  const int wave = tid >> 6;
  const int lane = tid & 63;
  const int l15  = lane & 15;
  const int quad = lane >> 4;
  const int wm = wave >> 1, wn = wave & 1;

  const size_t aOff = (size_t)(bm * 128 + wave * 32 + (lane >> 2)) * K + (lane & 3) * 8;
  const size_t bOff = (size_t)(bn * 128 + wave * 32 + (lane >> 2)) * K + (lane & 3) * 8;
  const int ldsOff0 = (wave * 32) * 32;
  const int ldsOff1 = (wave * 32 + 16) * 32;

  f32x4 acc[4][4];
  #pragma unroll
  for (int i = 0; i < 4; i++)
    #pragma unroll
    for (int j = 0; j < 4; j++) acc[i][j] = (f32x4){0.f, 0.f, 0.f, 0.f};

  for (int kt = 0; kt < K; kt += 32) {
    async_copy16(Ah + aOff + kt, &AsH[ldsOff0]);
    async_copy16(Ah + aOff + kt + (size_t)16 * K, &AsH[ldsOff1]);
    async_copy16(Al + aOff + kt, &AsL[ldsOff0]);
    async_copy16(Al + aOff + kt + (size_t)16 * K, &AsL[ldsOff1]);
    async_copy16(Bh + bOff + kt, &BsH[ldsOff0]);
    async_copy16(Bh + bOff + kt + (size_t)16 * K, &BsH[ldsOff1]);
    async_copy16(Bl + bOff + kt, &BsL[ldsOff0]);
    async_copy16(Bl + bOff + kt + (size_t)16 * K, &BsL[ldsOff1]);
    __syncthreads();
    bf16x8 afH[4], afL[4], bfH[4], bfL[4];
    #pragma unroll
    for (int i = 0; i < 4; i++) {
      const int o = (wm * 64 + i * 16 + l15) * 32 + quad * 8;
      afH[i] = *(const bf16x8*)&AsH[o];
      afL[i] = *(const bf16x8*)&AsL[o];
    }
    #pragma unroll
    for (int j = 0; j < 4; j++) {
      const int o = (wn * 64 + j * 16 + l15) * 32 + quad * 8;
      bfH[j] = *(const bf16x8*)&BsH[o];
      bfL[j] = *(const bf16x8*)&BsL[o];
    }
    #pragma unroll
    for (int i = 0; i < 4; i++)
      #pragma unroll
      for (int j = 0; j < 4; j++) {
        acc[i][j] = __builtin_amdgcn_mfma_f32_16x16x32_bf16(afH[i], bfH[j], acc[i][j], 0, 0, 0);
        acc[i][j] = __builtin_amdgcn_mfma_f32_16x16x32_bf16(afH[i], bfL[j], acc[i][j], 0, 0, 0);
        acc[i][j] = __builtin_amdgcn_mfma_f32_16x16x32_bf16(afL[i], bfH[j], acc[i][j], 0, 0, 0);
      }
    __syncthreads();
  }

  const int gm0 = bm * 128 + wm * 64 + quad * 4;
  const int gn0 = bn * 128 + wn * 64 + l15;
  #pragma unroll
  for (int i = 0; i < 4; i++)
    #pragma unroll
    for (int j = 0; j < 4; j++) {
      const int gn = gn0 + j * 16;
      const float scale = (gn < 1024) ? QSCALE : 1.0f;  // q cols get 8*log2e
      #pragma unroll
      for (int r = 0; r < 4; r++) {
        const int gm = gm0 + i * 16 + r;
        bf16_t hi, lo;
        split_bf16(acc[i][j][r] * scale, hi, lo);
        out_hi[(size_t)gm * N + gn] = hi;
        out_lo[(size_t)gm * N + gn] = lo;
      }
    }
}

// ---------------- Flash attention v4: two-pass fixed-M softmax.
// grid (32 qtiles, 16 heads, 4 batch), block 256 (4 waves x 16 queries).
// Scores arrive in log2 units (q prescaled by 8*log2e in QK-gemm epilogue).
__global__ __launch_bounds__(256) void attn_kernel(
    const bf16_t* __restrict__ qkH,  // [8192][2048] q' cols 0..1023, k cols 1024..2047
    const bf16_t* __restrict__ qkL,
    const bf16_t* __restrict__ vT,   // [(b*1024+n)][2048]
    bf16_t* __restrict__ o)          // [8192][1024]
{
  const int qt = blockIdx.x;
  const int h  = blockIdx.y;
  const int b  = blockIdx.z;
  const int wave = threadIdx.x >> 6;
  const int lane = threadIdx.x & 63;
  const int l15  = lane & 15;
  const int quad = lane >> 4;
  const int qrow = qt * 64 + wave * 16;
  const int sw   = l15 & 7;

  __shared__ __align__(16) bf16_t KhL[128 * 64];  // pass1 uses 128 rows; pass2 first 64
  __shared__ __align__(16) bf16_t KlL[64 * 64];
  __shared__ __align__(16) bf16_t VtL[64 * 64];   // [dim][key]
  __shared__ __align__(16) bf16_t Pl[4][16 * 64]; // per-wave P [q][key]

  const size_t tok0 = (size_t)b * 2048;
  const size_t qoff = (tok0 + qrow + l15) * 2048 + h * 64;
  const bf16x8 aq0H = *(const bf16x8*)(qkH + qoff + quad * 8);
  const bf16x8 aq1H = *(const bf16x8*)(qkH + qoff + 32 + quad * 8);
  const bf16x8 aq0L = *(const bf16x8*)(qkL + qoff + quad * 8);
  const bf16x8 aq1L = *(const bf16x8*)(qkL + qoff + 32 + quad * 8);

  const int   kOff  = 1024 + h * 64;
  const size_t vRow0 = (size_t)b * 1024 + h * 64;
  const int rsub = lane >> 3;
  const int csw  = (lane & 7) ^ (rsub & 7);

  // ---------- pass 1: per-row max estimate from hi*hi scores only.
  // Register max across all keys; one shfl chain at the end.
  f32x4 mx = (f32x4){-3.0e38f, -3.0e38f, -3.0e38f, -3.0e38f};
  for (int kb = 0; kb < 2048; kb += 128) {
    #pragma unroll
    for (int j = 0; j < 4; j++) {
      const int row0 = wave * 32 + j * 8;
      async_copy16(qkH + (tok0 + kb + row0 + rsub) * 2048 + kOff + csw * 8,
                   &KhL[row0 * 64]);
    }
    __syncthreads();
    #pragma unroll
    for (int t = 0; t < 8; t++) {
      const int base = (t * 16 + l15) * 64;
      const bf16x8 bh0 = *(const bf16x8*)&KhL[base + ((quad) ^ sw) * 8];
      const bf16x8 bh1 = *(const bf16x8*)&KhL[base + ((4 + quad) ^ sw) * 8];
      f32x4 acc = (f32x4){0.f, 0.f, 0.f, 0.f};
      acc = __builtin_amdgcn_mfma_f32_16x16x32_bf16(aq0H, bh0, acc, 0, 0, 0);
      acc = __builtin_amdgcn_mfma_f32_16x16x32_bf16(aq1H, bh1, acc, 0, 0, 0);
      #pragma unroll
      for (int r = 0; r < 4; r++) mx[r] = fmaxf(mx[r], acc[r]);
    }
    __syncthreads();
  }
  f32x4 negM;
  #pragma unroll
  for (int r = 0; r < 4; r++) {
    float m = mx[r];
    m = fmaxf(m, __shfl_xor(m, 1));
    m = fmaxf(m, __shfl_xor(m, 2));
    m = fmaxf(m, __shfl_xor(m, 4));
    m = fmaxf(m, __shfl_xor(m, 8));
    // +4 margin covers the dropped lo-term error (Cauchy-Schwarz bound ~3);
    // overestimating M is exactly correct (uniform scale cancels in l-divide).
    negM[r] = -(m + 4.0f);
  }

  // ---------- pass 2: p = exp2(score + negM); no rescaling, no per-chunk chains.
  f32x4 Of[4];
  f32x4 lsum = (f32x4){0.f, 0.f, 0.f, 0.f};
  #pragma unroll
  for (int c = 0; c < 4; c++) Of[c] = (f32x4){0.f, 0.f, 0.f, 0.f};
  bf16_t* pw = &Pl[wave][0];

  for (int kb = 0; kb < 2048; kb += 64) {
    #pragma unroll
    for (int j = 0; j < 2; j++) {
      const int row0 = wave * 16 + j * 8;
      const size_t krow = tok0 + kb + row0 + rsub;
      async_copy16(qkH + krow * 2048 + kOff + csw * 8, &KhL[row0 * 64]);
      async_copy16(qkL + krow * 2048 + kOff + csw * 8, &KlL[row0 * 64]);
      async_copy16(vT + (vRow0 + row0 + rsub) * 2048 + kb + csw * 8, &VtL[row0 * 64]);
    }
    __syncthreads();

    #pragma unroll
    for (int t = 0; t < 4; t++) {
      const int base = (t * 16 + l15) * 64;
      const bf16x8 bh0 = *(const bf16x8*)&KhL[base + ((quad) ^ sw) * 8];
      const bf16x8 bh1 = *(const bf16x8*)&KhL[base + ((4 + quad) ^ sw) * 8];
      const bf16x8 bl0 = *(const bf16x8*)&KlL[base + ((quad) ^ sw) * 8];
      const bf16x8 bl1 = *(const bf16x8*)&KlL[base + ((4 + quad) ^ sw) * 8];
      f32x4 acc = negM;  // fold -M into accumulator init (free)
      acc = __builtin_amdgcn_mfma_f32_16x16x32_bf16(aq0H, bh0, acc, 0, 0, 0);
      acc = __builtin_amdgcn_mfma_f32_16x16x32_bf16(aq1H, bh1, acc, 0, 0, 0);
      acc = __builtin_amdgcn_mfma_f32_16x16x32_bf16(aq0H, bl0, acc, 0, 0, 0);
      acc = __builtin_amdgcn_mfma_f32_16x16x32_bf16(aq1H, bl1, acc, 0, 0, 0);
      acc = __builtin_amdgcn_mfma_f32_16x16x32_bf16(aq0L, bh0, acc, 0, 0, 0);
      acc = __builtin_amdgcn_mfma_f32_16x16x32_bf16(aq1L, bh1, acc, 0, 0, 0);
      #pragma unroll
      for (int r = 0; r < 4; r++) {
        const float p = __builtin_amdgcn_exp2f(acc[r]);
        lsum[r] += p;
        const int R = quad * 4 + r;
        pw[R * 64 + (((t * 2 + (l15 >> 3)) ^ (R & 7)) * 8) + (l15 & 7)] =
            __float2bfloat16(p);
      }
    }

    // PV (P round-trip is same-wave: no barrier needed)
    const bf16x8 pa0 = *(const bf16x8*)&pw[l15 * 64 + ((quad) ^ sw) * 8];
    const bf16x8 pa1 = *(const bf16x8*)&pw[l15 * 64 + ((4 + quad) ^ sw) * 8];
    #pragma unroll
    for (int c = 0; c < 4; c++) {
      const int vb = (c * 16 + l15) * 64;
      const bf16x8 bv0 = *(const bf16x8*)&VtL[vb + ((quad) ^ sw) * 8];
      const bf16x8 bv1 = *(const bf16x8*)&VtL[vb + ((4 + quad) ^ sw) * 8];
      Of[c] = __builtin_amdgcn_mfma_f32_16x16x32_bf16(pa0, bv0, Of[c], 0, 0, 0);
      Of[c] = __builtin_amdgcn_mfma_f32_16x16x32_bf16(pa1, bv1, Of[c], 0, 0, 0);
    }
    __syncthreads();
  }

  float lrow[4];
  #pragma unroll
  for (int r = 0; r < 4; r++) {
    float cs = lsum[r];
    cs += __shfl_xor(cs, 1);
    cs += __shfl_xor(cs, 2);
    cs += __shfl_xor(cs, 4);
    cs += __shfl_xor(cs, 8);
    lrow[r] = cs;
  }

  bf16_t* op = o + (tok0 + qrow) * 1024 + h * 64;
  #pragma unroll
  for (int c = 0; c < 4; c++)
    #pragma unroll
    for (int r = 0; r < 4; r++) {
      const float val = Of[c][r] / lrow[r];
      op[(size_t)(quad * 4 + r) * 1024 + c * 16 + l15] = __float2bfloat16(val);
    }
}

extern "C" void kernel_launch(void* const* d_in, const int* in_sizes, int n_in,
                              void* d_out, int out_size, void* d_ws, size_t ws_size,
                              hipStream_t stream)
{
  (void)in_sizes; (void)n_in; (void)out_size; (void)ws_size;
  const float* x   = (const float*)d_in[0];
  const float* Wk  = (const float*)d_in[2];
  const float* Wq  = (const float*)d_in[3];
  const float* Wv  = (const float*)d_in[4];
  const float* Wfc = (const float*)d_in[5];
  const float* bfc = (const float*)d_in[6];
  const float* g1  = (const float*)d_in[7];
  const float* b1  = (const float*)d_in[8];
  const float* g2  = (const float*)d_in[9];
  const float* b2  = (const float*)d_in[10];
  const float* W1  = (const float*)d_in[11];
  const float* bf1 = (const float*)d_in[12];
  const float* W2  = (const float*)d_in[13];
  const float* bf2 = (const float*)d_in[14];
  float* out = (float*)d_out;

  char* ws = (char*)d_ws;
  bf16_t* xl_hi  = (bf16_t*)(ws + (0ull   << 20));
  bf16_t* oAtt   = xl_hi;
  bf16_t* xl_lo  = (bf16_t*)(ws + (16ull  << 20));
  bf16_t* vT     = xl_lo;
  bf16_t* xl2    = xl_lo;
  bf16_t* qk_hi  = (bf16_t*)(ws + (32ull  << 20));
  bf16_t* qk_lo  = (bf16_t*)(ws + (64ull  << 20));
  bf16_t* h1     = qk_hi;
  bf16_t* v      = (bf16_t*)(ws + (96ull  << 20));
  float*  x2     = (float*) (ws + (112ull << 20));
  bf16_t* Wqk_hi = (bf16_t*)(ws + (144ull << 20));
  bf16_t* Wqk_lo = (bf16_t*)(ws + (148ull << 20));
  bf16_t* WvT    = (bf16_t*)(ws + (152ull << 20));
  bf16_t* WfcT   = (bf16_t*)(ws + (154ull << 20));
  bf16_t* W1T    = (bf16_t*)(ws + (156ull << 20));
  bf16_t* W2T    = (bf16_t*)(ws + (164ull << 20));

  const dim3 blk(256);

  wtrans_kernel<true ><<<dim3(32, 32),  blk, 0, stream>>>(Wq,  Wqk_hi,               Wqk_lo,               1024, 1024);
  wtrans_kernel<true ><<<dim3(32, 32),  blk, 0, stream>>>(Wk,  Wqk_hi + 1024 * 1024, Wqk_lo + 1024 * 1024, 1024, 1024);
  wtrans_kernel<false><<<dim3(32, 32),  blk, 0, stream>>>(Wv,  WvT,  nullptr, 1024, 1024);
  wtrans_kernel<false><<<dim3(32, 32),  blk, 0, stream>>>(Wfc, WfcT, nullptr, 1024, 1024);
  wtrans_kernel<false><<<dim3(128, 32), blk, 0, stream>>>(W1,  W1T,  nullptr, 1024, 4096);
  wtrans_kernel<false><<<dim3(32, 128), blk, 0, stream>>>(W2,  W2T,  nullptr, 4096, 1024);

  ln_kernel<true><<<8192, blk, 0, stream>>>(x, g1, b1, xl_hi, xl_lo);

  gemm_split_kernel<<<64 * 16, blk, 0, stream>>>(
      xl_hi, xl_lo, Wqk_hi, Wqk_lo, qk_hi, qk_lo, 8192, 2048, 1024);

  gemm_kernel<false, false, false, true><<<64 * 8, blk, 0, stream>>>(
      xl_hi, WvT, nullptr, nullptr, nullptr, v, 8192, 1024, 1024);

  vtrans_kernel<<<dim3(64, 32, 4), blk, 0, stream>>>(v, vT);

  attn_kernel<<<dim3(32, 16, 4), blk, 0, stream>>>(qk_hi, qk_lo, vT, oAtt);

  gemm_kernel<true, false, true, false><<<64 * 8, blk, 0, stream>>>(
      oAtt, WfcT, bfc, x, x2, nullptr, 8192, 1024, 1024);

  ln_kernel<false><<<8192, blk, 0, stream>>>(x2, g2, b2, xl2, nullptr);

  gemm_kernel<true, true, false, true><<<64 * 32, blk, 0, stream>>>(
      xl2, W1T, bf1, nullptr, nullptr, h1, 8192, 4096, 1024);

  gemm_kernel<true, false, true, false><<<64 * 8, blk, 0, stream>>>(
      h1, W2T, bf2, x2, out, nullptr, 8192, 1024, 4096);
}

// Round 5
// 736.210 us; speedup vs baseline: 1.6560x; 1.0707x over previous
//
#include <hip/hip_runtime.h>
#include <hip/hip_bf16.h>
#include <math.h>

// EncoderLayer for MI355X (gfx950).
// Numerics: scores = q.k * sqrt(C)=8 (reference quirk) => logits ~N(0,64^2),
// near-one-hot softmax => q,k computed/consumed in SPLIT bf16 (hi+lo ~= fp32).
// Attention: TWO-PASS softmax with fixed per-row M (pass1 hi*hi estimate + 4;
// fixed M cancels in the l-divide, so overestimate is exact). 8*log2e folded
// into q in the QK-gemm epilogue.
// R5: attn does 2 q-tiles per wave (64 MFMA per staged chunk, K traffic /2);
// V-gemm emits V^T directly (A=WvT, BT=xl_hi, M=1024,N=8192) -- vtrans deleted.

typedef __hip_bfloat16 bf16_t;
typedef __bf16 bf16x8 __attribute__((ext_vector_type(8)));
typedef float f32x4 __attribute__((ext_vector_type(4)));

#define LN_EPS 1e-5f
#define QSCALE 11.541560327111707f  // 8 * log2(e)

__device__ __forceinline__ void async_copy16(const bf16_t* g, bf16_t* l) {
  __builtin_amdgcn_global_load_lds(
      (const __attribute__((address_space(1))) void*)g,
      (__attribute__((address_space(3))) void*)l,
      16 /*bytes*/, 0 /*offset*/, 0 /*aux*/);
}

__device__ __forceinline__ void split_bf16(float v, bf16_t& hi, bf16_t& lo) {
  hi = __float2bfloat16(v);
  lo = __float2bfloat16(v - __bfloat162float(hi));
}

// ---------------- LayerNorm: fp32 in -> bf16 out (one block per row of 1024)
template<bool SPLIT>
__global__ __launch_bounds__(256) void ln_kernel(
    const float* __restrict__ x, const float* __restrict__ g,
    const float* __restrict__ b, bf16_t* __restrict__ out_hi,
    bf16_t* __restrict__ out_lo)
{
  const int row = blockIdx.x;
  const int tid = threadIdx.x;
  const float4 v = *(const float4*)(x + (size_t)row * 1024 + tid * 4);
  float s  = v.x + v.y + v.z + v.w;
  float ss = v.x * v.x + v.y * v.y + v.z * v.z + v.w * v.w;
  for (int off = 32; off > 0; off >>= 1) {
    s  += __shfl_down(s, off);
    ss += __shfl_down(ss, off);
  }
  __shared__ float sb[4], ssb[4];
  const int wave = tid >> 6, lane = tid & 63;
  if (lane == 0) { sb[wave] = s; ssb[wave] = ss; }
  __syncthreads();
  const float tot  = sb[0] + sb[1] + sb[2] + sb[3];
  const float tots = ssb[0] + ssb[1] + ssb[2] + ssb[3];
  const float mu   = tot * (1.0f / 1024.0f);
  const float var  = tots * (1.0f / 1024.0f) - mu * mu;
  const float rstd = rsqrtf(var + LN_EPS);
  const float4 gv = *(const float4*)(g + tid * 4);
  const float4 bv = *(const float4*)(b + tid * 4);
  float y[4] = {(v.x - mu) * rstd * gv.x + bv.x,
                (v.y - mu) * rstd * gv.y + bv.y,
                (v.z - mu) * rstd * gv.z + bv.z,
                (v.w - mu) * rstd * gv.w + bv.w};
  bf16_t hi[4] __attribute__((aligned(8)));
  bf16_t lo[4] __attribute__((aligned(8)));
  #pragma unroll
  for (int i = 0; i < 4; i++) split_bf16(y[i], hi[i], lo[i]);
  uint2 ph, pl;
  __builtin_memcpy(&ph, hi, 8);
  *(uint2*)(out_hi + (size_t)row * 1024 + tid * 4) = ph;
  if (SPLIT) {
    __builtin_memcpy(&pl, lo, 8);
    *(uint2*)(out_lo + (size_t)row * 1024 + tid * 4) = pl;
  }
}

// ---------------- Weight transpose + cast: W (KxN fp32) -> WT (NxK bf16[, lo])
template<bool SPLIT>
__global__ __launch_bounds__(256) void wtrans_kernel(
    const float* __restrict__ W, bf16_t* __restrict__ WT_hi,
    bf16_t* __restrict__ WT_lo, int K, int N)
{
  __shared__ float t[32][33];
  const int n0 = blockIdx.x * 32, k0 = blockIdx.y * 32;
  const int tx = threadIdx.x & 31, ty = threadIdx.x >> 5;
  #pragma unroll
  for (int r = ty; r < 32; r += 8)
    t[r][tx] = W[(size_t)(k0 + r) * N + n0 + tx];
  __syncthreads();
  #pragma unroll
  for (int r = ty; r < 32; r += 8) {
    const float v = t[tx][r];
    bf16_t hi, lo;
    split_bf16(v, hi, lo);
    WT_hi[(size_t)(n0 + r) * K + k0 + tx] = hi;
    if (SPLIT) WT_lo[(size_t)(n0 + r) * K + k0 + tx] = lo;
  }
}

// ---------------- GEMM: C(MxN) = A(MxK,bf16) * BT(NxK,bf16)^T [+bias][+resid][relu]
template<bool BIAS, bool RELU, bool RESID, bool OUTBF>
__global__ __launch_bounds__(256) void gemm_kernel(
    const bf16_t* __restrict__ A, const bf16_t* __restrict__ BT,
    const float* __restrict__ bias, const float* __restrict__ resid,
    float* __restrict__ outF, bf16_t* __restrict__ outB,
    int M, int N, int K)
{
  __shared__ __align__(16) bf16_t As[128 * 32];
  __shared__ __align__(16) bf16_t Bs[128 * 32];
  const int nblk = N >> 7;
  const int bm = blockIdx.x / nblk;
  const int bn = blockIdx.x % nblk;
  const int tid  = threadIdx.x;
  const int wave = tid >> 6;
  const int lane = tid & 63;
  const int l15  = lane & 15;
  const int quad = lane >> 4;
  const int wm = wave >> 1, wn = wave & 1;

  const bf16_t* aG = A  + (size_t)(bm * 128 + wave * 32 + (lane >> 2)) * K + (lane & 3) * 8;
  const bf16_t* bG = BT + (size_t)(bn * 128 + wave * 32 + (lane >> 2)) * K + (lane & 3) * 8;
  bf16_t* aL0 = &As[(wave * 32) * 32];
  bf16_t* aL1 = &As[(wave * 32 + 16) * 32];
  bf16_t* bL0 = &Bs[(wave * 32) * 32];
  bf16_t* bL1 = &Bs[(wave * 32 + 16) * 32];

  f32x4 acc[4][4];
  #pragma unroll
  for (int i = 0; i < 4; i++)
    #pragma unroll
    for (int j = 0; j < 4; j++) acc[i][j] = (f32x4){0.f, 0.f, 0.f, 0.f};

  for (int kt = 0; kt < K; kt += 32) {
    async_copy16(aG + kt, aL0);
    async_copy16(aG + kt + (size_t)16 * K, aL1);
    async_copy16(bG + kt, bL0);
    async_copy16(bG + kt + (size_t)16 * K, bL1);
    __syncthreads();
    bf16x8 af[4], bfr[4];
    #pragma unroll
    for (int i = 0; i < 4; i++)
      af[i]  = *(const bf16x8*)&As[(wm * 64 + i * 16 + l15) * 32 + quad * 8];
    #pragma unroll
    for (int j = 0; j < 4; j++)
      bfr[j] = *(const bf16x8*)&Bs[(wn * 64 + j * 16 + l15) * 32 + quad * 8];
    #pragma unroll
    for (int i = 0; i < 4; i++)
      #pragma unroll
      for (int j = 0; j < 4; j++)
        acc[i][j] = __builtin_amdgcn_mfma_f32_16x16x32_bf16(af[i], bfr[j], acc[i][j], 0, 0, 0);
    __syncthreads();
  }

  const int gm0 = bm * 128 + wm * 64 + quad * 4;
  const int gn0 = bn * 128 + wn * 64 + l15;
  #pragma unroll
  for (int i = 0; i < 4; i++) {
    #pragma unroll
    for (int j = 0; j < 4; j++) {
      const int gn = gn0 + j * 16;
      const float bz = BIAS ? bias[gn] : 0.0f;
      #pragma unroll
      for (int r = 0; r < 4; r++) {
        const int gm = gm0 + i * 16 + r;
        float v = acc[i][j][r] + bz;
        if (RESID) v += resid[(size_t)gm * N + gn];
        if (RELU)  v = fmaxf(v, 0.0f);
        if (OUTBF) outB[(size_t)gm * N + gn] = __float2bfloat16(v);
        else       outF[(size_t)gm * N + gn] = v;
      }
    }
  }
}

// ---------------- Split-precision GEMM for q,k.
// Epilogue scales q columns (gn<1024) by 8*log2e in fp32 BEFORE re-splitting.
__global__ __launch_bounds__(256) void gemm_split_kernel(
    const bf16_t* __restrict__ Ah, const bf16_t* __restrict__ Al,
    const bf16_t* __restrict__ Bh, const bf16_t* __restrict__ Bl,
    bf16_t* __restrict__ out_hi, bf16_t* __restrict__ out_lo,
    int M, int N, int K)
{
  __shared__ __align__(16) bf16_t AsH[128 * 32];
  __shared__ __align__(16) bf16_t AsL[128 * 32];
  __shared__ __align__(16) bf16_t BsH[128 * 32];
  __shared__ __align__(16) bf16_t BsL[128 * 32];
  const int nblk = N >> 7;
  const int bm = blockIdx.x / nblk;
  const int bn = blockIdx.x % nblk;
  const int tid  = threadIdx.x;
  const int wave = tid >> 6;
  const int lane = tid & 63;
  const int l15  = lane & 15;
  const int quad = lane >> 4;
  const int wm = wave >> 1, wn = wave & 1;

  const size_t aOff = (size_t)(bm * 128 + wave * 32 + (lane >> 2)) * K + (lane & 3) * 8;
  const size_t bOff = (size_t)(bn * 128 + wave * 32 + (lane >> 2)) * K + (lane & 3) * 8;
  const int ldsOff0 = (wave * 32) * 32;
  const int ldsOff1 = (wave * 32 + 16) * 32;

  f32x4 acc[4][4];
  #pragma unroll
  for (int i = 0; i < 4; i++)
    #pragma unroll
    for (int j = 0; j < 4; j++) acc[i][j] = (f32x4){0.f, 0.f, 0.f, 0.f};

  for (int kt = 0; kt < K; kt += 32) {
    async_copy16(Ah + aOff + kt, &AsH[ldsOff0]);
    async_copy16(Ah + aOff + kt + (size_t)16 * K, &AsH[ldsOff1]);
    async_copy16(Al + aOff + kt, &AsL[ldsOff0]);
    async_copy16(Al + aOff + kt + (size_t)16 * K, &AsL[ldsOff1]);
    async_copy16(Bh + bOff + kt, &BsH[ldsOff0]);
    async_copy16(Bh + bOff + kt + (size_t)16 * K, &BsH[ldsOff1]);
    async_copy16(Bl + bOff + kt, &BsL[ldsOff0]);
    async_copy16(Bl + bOff + kt + (size_t)16 * K, &BsL[ldsOff1]);
    __syncthreads();
    bf16x8 afH[4], afL[4], bfH[4], bfL[4];
    #pragma unroll
    for (int i = 0; i < 4; i++) {
      const int o = (wm * 64 + i * 16 + l15) * 32 + quad * 8;
      afH[i] = *(const bf16x8*)&AsH[o];
      afL[i] = *(const bf16x8*)&AsL[o];
    }
    #pragma unroll
    for (int j = 0; j < 4; j++) {
      const int o = (wn * 64 + j * 16 + l15) * 32 + quad * 8;
      bfH[j] = *(const bf16x8*)&BsH[o];
      bfL[j] = *(const bf16x8*)&BsL[o];
    }
    #pragma unroll
    for (int i = 0; i < 4; i++)
      #pragma unroll
      for (int j = 0; j < 4; j++) {
        acc[i][j] = __builtin_amdgcn_mfma_f32_16x16x32_bf16(afH[i], bfH[j], acc[i][j], 0, 0, 0);
        acc[i][j] = __builtin_amdgcn_mfma_f32_16x16x32_bf16(afH[i], bfL[j], acc[i][j], 0, 0, 0);
        acc[i][j] = __builtin_amdgcn_mfma_f32_16x16x32_bf16(afL[i], bfH[j], acc[i][j], 0, 0, 0);
      }
    __syncthreads();
  }

  const int gm0 = bm * 128 + wm * 64 + quad * 4;
  const int gn0 = bn * 128 + wn * 64 + l15;
  #pragma unroll
  for (int i = 0; i < 4; i++)
    #pragma unroll
    for (int j = 0; j < 4; j++) {
      const int gn = gn0 + j * 16;
      const float scale = (gn < 1024) ? QSCALE : 1.0f;
      #pragma unroll
      for (int r = 0; r < 4; r++) {
        const int gm = gm0 + i * 16 + r;
        bf16_t hi, lo;
        split_bf16(acc[i][j][r] * scale, hi, lo);
        out_hi[(size_t)gm * N + gn] = hi;
        out_lo[(size_t)gm * N + gn] = lo;
      }
    }
}

// ---------------- Flash attention v5: two-pass fixed-M softmax, 2 q-tiles/wave.
// grid (16 qtiles, 16 heads, 4 batch), block 256 (4 waves x 32 queries).
// Scores arrive in log2 units (q prescaled by 8*log2e in QK-gemm epilogue).
// vT layout: [dim 0..1023][tok 0..8191]  (row = h*64+c, col = b*2048+s)
__global__ __launch_bounds__(256) void attn_kernel(
    const bf16_t* __restrict__ qkH,  // [8192][2048] q' cols 0..1023, k cols 1024..2047
    const bf16_t* __restrict__ qkL,
    const bf16_t* __restrict__ vT,   // [1024][8192]
    bf16_t* __restrict__ o)          // [8192][1024]
{
  const int qt = blockIdx.x;
  const int h  = blockIdx.y;
  const int b  = blockIdx.z;
  const int wave = threadIdx.x >> 6;
  const int lane = threadIdx.x & 63;
  const int l15  = lane & 15;
  const int quad = lane >> 4;
  const int sw   = l15 & 7;
  const int qrowA = qt * 128 + wave * 32;  // first q-tile
  const int qrowB = qrowA + 16;            // second q-tile

  __shared__ __align__(16) bf16_t KhL[64 * 64];
  __shared__ __align__(16) bf16_t KlL[64 * 64];
  __shared__ __align__(16) bf16_t VtL[64 * 64];   // [dim][key]
  __shared__ __align__(16) bf16_t Pl[4][32 * 64]; // per-wave P [q 0..31][key]

  const size_t tok0 = (size_t)b * 2048;
  const size_t qoffA = (tok0 + qrowA + l15) * 2048 + h * 64;
  const size_t qoffB = (tok0 + qrowB + l15) * 2048 + h * 64;
  const bf16x8 aA0H = *(const bf16x8*)(qkH + qoffA + quad * 8);
  const bf16x8 aA1H = *(const bf16x8*)(qkH + qoffA + 32 + quad * 8);
  const bf16x8 aA0L = *(const bf16x8*)(qkL + qoffA + quad * 8);
  const bf16x8 aA1L = *(const bf16x8*)(qkL + qoffA + 32 + quad * 8);
  const bf16x8 aB0H = *(const bf16x8*)(qkH + qoffB + quad * 8);
  const bf16x8 aB1H = *(const bf16x8*)(qkH + qoffB + 32 + quad * 8);
  const bf16x8 aB0L = *(const bf16x8*)(qkL + qoffB + quad * 8);
  const bf16x8 aB1L = *(const bf16x8*)(qkL + qoffB + 32 + quad * 8);

  const int kOff = 1024 + h * 64;
  const int rsub = lane >> 3;
  const int csw  = (lane & 7) ^ (rsub & 7);

  // ---------- pass 1: per-row max estimate from hi*hi scores only.
  f32x4 mxA = (f32x4){-3.0e38f, -3.0e38f, -3.0e38f, -3.0e38f};
  f32x4 mxB = mxA;
  for (int kb = 0; kb < 2048; kb += 64) {
    #pragma unroll
    for (int j = 0; j < 2; j++) {
      const int row0 = wave * 16 + j * 8;
      async_copy16(qkH + (tok0 + kb + row0 + rsub) * 2048 + kOff + csw * 8,
                   &KhL[row0 * 64]);
    }
    __syncthreads();
    #pragma unroll
    for (int t = 0; t < 4; t++) {
      const int base = (t * 16 + l15) * 64;
      const bf16x8 bh0 = *(const bf16x8*)&KhL[base + ((quad) ^ sw) * 8];
      const bf16x8 bh1 = *(const bf16x8*)&KhL[base + ((4 + quad) ^ sw) * 8];
      f32x4 accA = (f32x4){0.f, 0.f, 0.f, 0.f};
      f32x4 accB = accA;
      accA = __builtin_amdgcn_mfma_f32_16x16x32_bf16(aA0H, bh0, accA, 0, 0, 0);
      accA = __builtin_amdgcn_mfma_f32_16x16x32_bf16(aA1H, bh1, accA, 0, 0, 0);
      accB = __builtin_amdgcn_mfma_f32_16x16x32_bf16(aB0H, bh0, accB, 0, 0, 0);
      accB = __builtin_amdgcn_mfma_f32_16x16x32_bf16(aB1H, bh1, accB, 0, 0, 0);
      #pragma unroll
      for (int r = 0; r < 4; r++) {
        mxA[r] = fmaxf(mxA[r], accA[r]);
        mxB[r] = fmaxf(mxB[r], accB[r]);
      }
    }
    __syncthreads();
  }
  f32x4 negMA, negMB;
  #pragma unroll
  for (int r = 0; r < 4; r++) {
    float mA = mxA[r], mB = mxB[r];
    mA = fmaxf(mA, __shfl_xor(mA, 1)); mB = fmaxf(mB, __shfl_xor(mB, 1));
    mA = fmaxf(mA, __shfl_xor(mA, 2)); mB = fmaxf(mB, __shfl_xor(mB, 2));
    mA = fmaxf(mA, __shfl_xor(mA, 4)); mB = fmaxf(mB, __shfl_xor(mB, 4));
    mA = fmaxf(mA, __shfl_xor(mA, 8)); mB = fmaxf(mB, __shfl_xor(mB, 8));
    // +4 covers dropped lo-term error; overestimate cancels in l-divide.
    negMA[r] = -(mA + 4.0f);
    negMB[r] = -(mB + 4.0f);
  }

  // ---------- pass 2
  f32x4 OfA[4], OfB[4];
  f32x4 lsumA = (f32x4){0.f, 0.f, 0.f, 0.f};
  f32x4 lsumB = lsumA;
  #pragma unroll
  for (int c = 0; c < 4; c++) { OfA[c] = lsumA; OfB[c] = lsumA; }
  bf16_t* pw = &Pl[wave][0];

  for (int kb = 0; kb < 2048; kb += 64) {
    #pragma unroll
    for (int j = 0; j < 2; j++) {
      const int row0 = wave * 16 + j * 8;
      const size_t krow = tok0 + kb + row0 + rsub;
      async_copy16(qkH + krow * 2048 + kOff + csw * 8, &KhL[row0 * 64]);
      async_copy16(qkL + krow * 2048 + kOff + csw * 8, &KlL[row0 * 64]);
      async_copy16(vT + (size_t)(h * 64 + row0 + rsub) * 8192 + tok0 + kb + csw * 8,
                   &VtL[row0 * 64]);
    }
    __syncthreads();

    #pragma unroll
    for (int t = 0; t < 4; t++) {
      const int base = (t * 16 + l15) * 64;
      const bf16x8 bh0 = *(const bf16x8*)&KhL[base + ((quad) ^ sw) * 8];
      const bf16x8 bh1 = *(const bf16x8*)&KhL[base + ((4 + quad) ^ sw) * 8];
      const bf16x8 bl0 = *(const bf16x8*)&KlL[base + ((quad) ^ sw) * 8];
      const bf16x8 bl1 = *(const bf16x8*)&KlL[base + ((4 + quad) ^ sw) * 8];
      f32x4 accA = negMA;
      f32x4 accB = negMB;
      accA = __builtin_amdgcn_mfma_f32_16x16x32_bf16(aA0H, bh0, accA, 0, 0, 0);
      accA = __builtin_amdgcn_mfma_f32_16x16x32_bf16(aA1H, bh1, accA, 0, 0, 0);
      accA = __builtin_amdgcn_mfma_f32_16x16x32_bf16(aA0H, bl0, accA, 0, 0, 0);
      accA = __builtin_amdgcn_mfma_f32_16x16x32_bf16(aA1H, bl1, accA, 0, 0, 0);
      accA = __builtin_amdgcn_mfma_f32_16x16x32_bf16(aA0L, bh0, accA, 0, 0, 0);
      accA = __builtin_amdgcn_mfma_f32_16x16x32_bf16(aA1L, bh1, accA, 0, 0, 0);
      accB = __builtin_amdgcn_mfma_f32_16x16x32_bf16(aB0H, bh0, accB, 0, 0, 0);
      accB = __builtin_amdgcn_mfma_f32_16x16x32_bf16(aB1H, bh1, accB, 0, 0, 0);
      accB = __builtin_amdgcn_mfma_f32_16x16x32_bf16(aB0H, bl0, accB, 0, 0, 0);
      accB = __builtin_amdgcn_mfma_f32_16x16x32_bf16(aB1H, bl1, accB, 0, 0, 0);
      accB = __builtin_amdgcn_mfma_f32_16x16x32_bf16(aB0L, bh0, accB, 0, 0, 0);
      accB = __builtin_amdgcn_mfma_f32_16x16x32_bf16(aB1L, bh1, accB, 0, 0, 0);
      #pragma unroll
      for (int r = 0; r < 4; r++) {
        const float pA = __builtin_amdgcn_exp2f(accA[r]);
        const float pB = __builtin_amdgcn_exp2f(accB[r]);
        lsumA[r] += pA;
        lsumB[r] += pB;
        const int RA = quad * 4 + r;
        const int RB = 16 + RA;
        pw[RA * 64 + (((t * 2 + (l15 >> 3)) ^ (RA & 7)) * 8) + (l15 & 7)] =
            __float2bfloat16(pA);
        pw[RB * 64 + (((t * 2 + (l15 >> 3)) ^ (RB & 7)) * 8) + (l15 & 7)] =
            __float2bfloat16(pB);
      }
    }

    // PV (P round-trip is same-wave: no barrier needed)
    const bf16x8 paA0 = *(const bf16x8*)&pw[l15 * 64 + ((quad) ^ sw) * 8];
    const bf16x8 paA1 = *(const bf16x8*)&pw[l15 * 64 + ((4 + quad) ^ sw) * 8];
    const bf16x8 paB0 = *(const bf16x8*)&pw[(16 + l15) * 64 + ((quad) ^ sw) * 8];
    const bf16x8 paB1 = *(const bf16x8*)&pw[(16 + l15) * 64 + ((4 + quad) ^ sw) * 8];
    #pragma unroll
    for (int c = 0; c < 4; c++) {
      const int vb = (c * 16 + l15) * 64;
      const bf16x8 bv0 = *(const bf16x8*)&VtL[vb + ((quad) ^ sw) * 8];
      const bf16x8 bv1 = *(const bf16x8*)&VtL[vb + ((4 + quad) ^ sw) * 8];
      OfA[c] = __builtin_amdgcn_mfma_f32_16x16x32_bf16(paA0, bv0, OfA[c], 0, 0, 0);
      OfA[c] = __builtin_amdgcn_mfma_f32_16x16x32_bf16(paA1, bv1, OfA[c], 0, 0, 0);
      OfB[c] = __builtin_amdgcn_mfma_f32_16x16x32_bf16(paB0, bv0, OfB[c], 0, 0, 0);
      OfB[c] = __builtin_amdgcn_mfma_f32_16x16x32_bf16(paB1, bv1, OfB[c], 0, 0, 0);
    }
    __syncthreads();
  }

  float lrowA[4], lrowB[4];
  #pragma unroll
  for (int r = 0; r < 4; r++) {
    float cA = lsumA[r], cB = lsumB[r];
    cA += __shfl_xor(cA, 1); cB += __shfl_xor(cB, 1);
    cA += __shfl_xor(cA, 2); cB += __shfl_xor(cB, 2);
    cA += __shfl_xor(cA, 4); cB += __shfl_xor(cB, 4);
    cA += __shfl_xor(cA, 8); cB += __shfl_xor(cB, 8);
    lrowA[r] = cA; lrowB[r] = cB;
  }

  bf16_t* opA = o + (tok0 + qrowA) * 1024 + h * 64;
  bf16_t* opB = o + (tok0 + qrowB) * 1024 + h * 64;
  #pragma unroll
  for (int c = 0; c < 4; c++)
    #pragma unroll
    for (int r = 0; r < 4; r++) {
      opA[(size_t)(quad * 4 + r) * 1024 + c * 16 + l15] =
          __float2bfloat16(OfA[c][r] / lrowA[r]);
      opB[(size_t)(quad * 4 + r) * 1024 + c * 16 + l15] =
          __float2bfloat16(OfB[c][r] / lrowB[r]);
    }
}

extern "C" void kernel_launch(void* const* d_in, const int* in_sizes, int n_in,
                              void* d_out, int out_size, void* d_ws, size_t ws_size,
                              hipStream_t stream)
{
  (void)in_sizes; (void)n_in; (void)out_size; (void)ws_size;
  const float* x   = (const float*)d_in[0];
  const float* Wk  = (const float*)d_in[2];
  const float* Wq  = (const float*)d_in[3];
  const float* Wv  = (const float*)d_in[4];
  const float* Wfc = (const float*)d_in[5];
  const float* bfc = (const float*)d_in[6];
  const float* g1  = (const float*)d_in[7];
  const float* b1  = (const float*)d_in[8];
  const float* g2  = (const float*)d_in[9];
  const float* b2  = (const float*)d_in[10];
  const float* W1  = (const float*)d_in[11];
  const float* bf1 = (const float*)d_in[12];
  const float* W2  = (const float*)d_in[13];
  const float* bf2 = (const float*)d_in[14];
  float* out = (float*)d_out;

  // Workspace (aliased):
  //  @0   16MB: xl_hi -> oAtt
  //  @16  16MB: xl_lo -> vT (V^T [1024][8192]) -> xl2
  //  @32  64MB: qk_hi(32)+qk_lo(32) -> h1
  //  @112 32MB: x2
  //  @144 28MB: weights (Wqk hi/lo, WvT, WfcT, W1T, W2T)
  char* ws = (char*)d_ws;
  bf16_t* xl_hi  = (bf16_t*)(ws + (0ull   << 20));
  bf16_t* oAtt   = xl_hi;
  bf16_t* xl_lo  = (bf16_t*)(ws + (16ull  << 20));
  bf16_t* vT     = xl_lo;
  bf16_t* xl2    = xl_lo;
  bf16_t* qk_hi  = (bf16_t*)(ws + (32ull  << 20));
  bf16_t* qk_lo  = (bf16_t*)(ws + (64ull  << 20));
  bf16_t* h1     = qk_hi;
  float*  x2     = (float*) (ws + (112ull << 20));
  bf16_t* Wqk_hi = (bf16_t*)(ws + (144ull << 20));
  bf16_t* Wqk_lo = (bf16_t*)(ws + (148ull << 20));
  bf16_t* WvT    = (bf16_t*)(ws + (152ull << 20));
  bf16_t* WfcT   = (bf16_t*)(ws + (154ull << 20));
  bf16_t* W1T    = (bf16_t*)(ws + (156ull << 20));
  bf16_t* W2T    = (bf16_t*)(ws + (164ull << 20));

  const dim3 blk(256);

  wtrans_kernel<true ><<<dim3(32, 32),  blk, 0, stream>>>(Wq,  Wqk_hi,               Wqk_lo,               1024, 1024);
  wtrans_kernel<true ><<<dim3(32, 32),  blk, 0, stream>>>(Wk,  Wqk_hi + 1024 * 1024, Wqk_lo + 1024 * 1024, 1024, 1024);
  wtrans_kernel<false><<<dim3(32, 32),  blk, 0, stream>>>(Wv,  WvT,  nullptr, 1024, 1024);
  wtrans_kernel<false><<<dim3(32, 32),  blk, 0, stream>>>(Wfc, WfcT, nullptr, 1024, 1024);
  wtrans_kernel<false><<<dim3(128, 32), blk, 0, stream>>>(W1,  W1T,  nullptr, 1024, 4096);
  wtrans_kernel<false><<<dim3(32, 128), blk, 0, stream>>>(W2,  W2T,  nullptr, 4096, 1024);

  ln_kernel<true><<<8192, blk, 0, stream>>>(x, g1, b1, xl_hi, xl_lo);

  gemm_split_kernel<<<64 * 16, blk, 0, stream>>>(
      xl_hi, xl_lo, Wqk_hi, Wqk_lo, qk_hi, qk_lo, 8192, 2048, 1024);

  // V^T gemm: C[dim][tok] = WvT . xl_hi^T  (M=1024, N=8192)
  gemm_kernel<false, false, false, true><<<8 * 64, blk, 0, stream>>>(
      WvT, xl_hi, nullptr, nullptr, nullptr, vT, 1024, 8192, 1024);

  attn_kernel<<<dim3(16, 16, 4), blk, 0, stream>>>(qk_hi, qk_lo, vT, oAtt);

  gemm_kernel<true, false, true, false><<<64 * 8, blk, 0, stream>>>(
      oAtt, WfcT, bfc, x, x2, nullptr, 8192, 1024, 1024);

  ln_kernel<false><<<8192, blk, 0, stream>>>(x2, g2, b2, xl2, nullptr);

  gemm_kernel<true, true, false, true><<<64 * 32, blk, 0, stream>>>(
      xl2, W1T, bf1, nullptr, nullptr, h1, 8192, 4096, 1024);

  gemm_kernel<true, false, true, false><<<64 * 8, blk, 0, stream>>>(
      h1, W2T, bf2, x2, out, nullptr, 8192, 1024, 4096);
}

// Round 6
// 722.393 us; speedup vs baseline: 1.6876x; 1.0191x over previous
//
#include <hip/hip_runtime.h>
#include <hip/hip_bf16.h>
#include <math.h>

// EncoderLayer for MI355X (gfx950).
// Numerics: scores = q.k * sqrt(C)=8 (reference quirk) => logits ~N(0,64^2),
// near-one-hot softmax => q,k computed/consumed in SPLIT bf16 (hi+lo ~= fp32).
// Attention: TWO-PASS softmax with fixed per-row M (pass1 hi*hi estimate + 4;
// fixed M cancels in the l-divide, so overestimate is exact). 8*log2e folded
// into q in the QK-gemm epilogue.
// R6: pass-1 uses 256-key chunks through a 32KB LDS union (4x fewer barriers,
// 64 MFMA per barrier window); 6 weight-transpose launches fused into 1.

typedef __hip_bfloat16 bf16_t;
typedef __bf16 bf16x8 __attribute__((ext_vector_type(8)));
typedef float f32x4 __attribute__((ext_vector_type(4)));

#define LN_EPS 1e-5f
#define QSCALE 11.541560327111707f  // 8 * log2(e)

__device__ __forceinline__ void async_copy16(const bf16_t* g, bf16_t* l) {
  __builtin_amdgcn_global_load_lds(
      (const __attribute__((address_space(1))) void*)g,
      (__attribute__((address_space(3))) void*)l,
      16 /*bytes*/, 0 /*offset*/, 0 /*aux*/);
}

__device__ __forceinline__ void split_bf16(float v, bf16_t& hi, bf16_t& lo) {
  hi = __float2bfloat16(v);
  lo = __float2bfloat16(v - __bfloat162float(hi));
}

// ---------------- LayerNorm: fp32 in -> bf16 out (one block per row of 1024)
template<bool SPLIT>
__global__ __launch_bounds__(256) void ln_kernel(
    const float* __restrict__ x, const float* __restrict__ g,
    const float* __restrict__ b, bf16_t* __restrict__ out_hi,
    bf16_t* __restrict__ out_lo)
{
  const int row = blockIdx.x;
  const int tid = threadIdx.x;
  const float4 v = *(const float4*)(x + (size_t)row * 1024 + tid * 4);
  float s  = v.x + v.y + v.z + v.w;
  float ss = v.x * v.x + v.y * v.y + v.z * v.z + v.w * v.w;
  for (int off = 32; off > 0; off >>= 1) {
    s  += __shfl_down(s, off);
    ss += __shfl_down(ss, off);
  }
  __shared__ float sb[4], ssb[4];
  const int wave = tid >> 6, lane = tid & 63;
  if (lane == 0) { sb[wave] = s; ssb[wave] = ss; }
  __syncthreads();
  const float tot  = sb[0] + sb[1] + sb[2] + sb[3];
  const float tots = ssb[0] + ssb[1] + ssb[2] + ssb[3];
  const float mu   = tot * (1.0f / 1024.0f);
  const float var  = tots * (1.0f / 1024.0f) - mu * mu;
  const float rstd = rsqrtf(var + LN_EPS);
  const float4 gv = *(const float4*)(g + tid * 4);
  const float4 bv = *(const float4*)(b + tid * 4);
  float y[4] = {(v.x - mu) * rstd * gv.x + bv.x,
                (v.y - mu) * rstd * gv.y + bv.y,
                (v.z - mu) * rstd * gv.z + bv.z,
                (v.w - mu) * rstd * gv.w + bv.w};
  bf16_t hi[4] __attribute__((aligned(8)));
  bf16_t lo[4] __attribute__((aligned(8)));
  #pragma unroll
  for (int i = 0; i < 4; i++) split_bf16(y[i], hi[i], lo[i]);
  uint2 ph, pl;
  __builtin_memcpy(&ph, hi, 8);
  *(uint2*)(out_hi + (size_t)row * 1024 + tid * 4) = ph;
  if (SPLIT) {
    __builtin_memcpy(&pl, lo, 8);
    *(uint2*)(out_lo + (size_t)row * 1024 + tid * 4) = pl;
  }
}

// ---------------- Batched weight transpose + cast (all 6 weights, one launch)
// tile = 32x32. id ranges: [0,1024) Wq split, [1024,2048) Wk split,
// [2048,3072) Wv, [3072,4096) Wfc, [4096,8192) W1, [8192,12288) W2.
__global__ __launch_bounds__(256) void wtrans_all_kernel(
    const float* __restrict__ Wq, const float* __restrict__ Wk,
    const float* __restrict__ Wv, const float* __restrict__ Wfc,
    const float* __restrict__ W1, const float* __restrict__ W2,
    bf16_t* __restrict__ WqkH, bf16_t* __restrict__ WqkL,
    bf16_t* __restrict__ WvT, bf16_t* __restrict__ WfcT,
    bf16_t* __restrict__ W1T, bf16_t* __restrict__ W2T)
{
  const int id = blockIdx.x;
  const float* W; bf16_t* DH; bf16_t* DL = nullptr;
  int K, N, n0, k0;
  if (id < 4096) {
    K = 1024; N = 1024;
    const int local = id & 1023;
    n0 = (local & 31) * 32; k0 = (local >> 5) * 32;
    if (id < 1024)      { W = Wq;  DH = WqkH;                 DL = WqkL; }
    else if (id < 2048) { W = Wk;  DH = WqkH + 1024 * 1024;   DL = WqkL + 1024 * 1024; }
    else if (id < 3072) { W = Wv;  DH = WvT; }
    else                { W = Wfc; DH = WfcT; }
  } else if (id < 8192) {
    const int local = id - 4096;
    K = 1024; N = 4096; W = W1; DH = W1T;
    n0 = (local & 127) * 32; k0 = (local >> 7) * 32;
  } else {
    const int local = id - 8192;
    K = 4096; N = 1024; W = W2; DH = W2T;
    n0 = (local & 31) * 32; k0 = (local >> 5) * 32;
  }
  __shared__ float t[32][33];
  const int tx = threadIdx.x & 31, ty = threadIdx.x >> 5;
  #pragma unroll
  for (int r = ty; r < 32; r += 8)
    t[r][tx] = W[(size_t)(k0 + r) * N + n0 + tx];
  __syncthreads();
  #pragma unroll
  for (int r = ty; r < 32; r += 8) {
    const float v = t[tx][r];
    bf16_t hi, lo;
    split_bf16(v, hi, lo);
    DH[(size_t)(n0 + r) * K + k0 + tx] = hi;
    if (DL) DL[(size_t)(n0 + r) * K + k0 + tx] = lo;
  }
}

// ---------------- GEMM: C(MxN) = A(MxK,bf16) * BT(NxK,bf16)^T [+bias][+resid][relu]
template<bool BIAS, bool RELU, bool RESID, bool OUTBF>
__global__ __launch_bounds__(256) void gemm_kernel(
    const bf16_t* __restrict__ A, const bf16_t* __restrict__ BT,
    const float* __restrict__ bias, const float* __restrict__ resid,
    float* __restrict__ outF, bf16_t* __restrict__ outB,
    int M, int N, int K)
{
  __shared__ __align__(16) bf16_t As[128 * 32];
  __shared__ __align__(16) bf16_t Bs[128 * 32];
  const int nblk = N >> 7;
  const int bm = blockIdx.x / nblk;
  const int bn = blockIdx.x % nblk;
  const int tid  = threadIdx.x;
  const int wave = tid >> 6;
  const int lane = tid & 63;
  const int l15  = lane & 15;
  const int quad = lane >> 4;
  const int wm = wave >> 1, wn = wave & 1;

  const bf16_t* aG = A  + (size_t)(bm * 128 + wave * 32 + (lane >> 2)) * K + (lane & 3) * 8;
  const bf16_t* bG = BT + (size_t)(bn * 128 + wave * 32 + (lane >> 2)) * K + (lane & 3) * 8;
  bf16_t* aL0 = &As[(wave * 32) * 32];
  bf16_t* aL1 = &As[(wave * 32 + 16) * 32];
  bf16_t* bL0 = &Bs[(wave * 32) * 32];
  bf16_t* bL1 = &Bs[(wave * 32 + 16) * 32];

  f32x4 acc[4][4];
  #pragma unroll
  for (int i = 0; i < 4; i++)
    #pragma unroll
    for (int j = 0; j < 4; j++) acc[i][j] = (f32x4){0.f, 0.f, 0.f, 0.f};

  for (int kt = 0; kt < K; kt += 32) {
    async_copy16(aG + kt, aL0);
    async_copy16(aG + kt + (size_t)16 * K, aL1);
    async_copy16(bG + kt, bL0);
    async_copy16(bG + kt + (size_t)16 * K, bL1);
    __syncthreads();
    bf16x8 af[4], bfr[4];
    #pragma unroll
    for (int i = 0; i < 4; i++)
      af[i]  = *(const bf16x8*)&As[(wm * 64 + i * 16 + l15) * 32 + quad * 8];
    #pragma unroll
    for (int j = 0; j < 4; j++)
      bfr[j] = *(const bf16x8*)&Bs[(wn * 64 + j * 16 + l15) * 32 + quad * 8];
    #pragma unroll
    for (int i = 0; i < 4; i++)
      #pragma unroll
      for (int j = 0; j < 4; j++)
        acc[i][j] = __builtin_amdgcn_mfma_f32_16x16x32_bf16(af[i], bfr[j], acc[i][j], 0, 0, 0);
    __syncthreads();
  }

  const int gm0 = bm * 128 + wm * 64 + quad * 4;
  const int gn0 = bn * 128 + wn * 64 + l15;
  #pragma unroll
  for (int i = 0; i < 4; i++) {
    #pragma unroll
    for (int j = 0; j < 4; j++) {
      const int gn = gn0 + j * 16;
      const float bz = BIAS ? bias[gn] : 0.0f;
      #pragma unroll
      for (int r = 0; r < 4; r++) {
        const int gm = gm0 + i * 16 + r;
        float v = acc[i][j][r] + bz;
        if (RESID) v += resid[(size_t)gm * N + gn];
        if (RELU)  v = fmaxf(v, 0.0f);
        if (OUTBF) outB[(size_t)gm * N + gn] = __float2bfloat16(v);
        else       outF[(size_t)gm * N + gn] = v;
      }
    }
  }
}

// ---------------- Split-precision GEMM for q,k.
// Epilogue scales q columns (gn<1024) by 8*log2e in fp32 BEFORE re-splitting.
__global__ __launch_bounds__(256) void gemm_split_kernel(
    const bf16_t* __restrict__ Ah, const bf16_t* __restrict__ Al,
    const bf16_t* __restrict__ Bh, const bf16_t* __restrict__ Bl,
    bf16_t* __restrict__ out_hi, bf16_t* __restrict__ out_lo,
    int M, int N, int K)
{
  __shared__ __align__(16) bf16_t AsH[128 * 32];
  __shared__ __align__(16) bf16_t AsL[128 * 32];
  __shared__ __align__(16) bf16_t BsH[128 * 32];
  __shared__ __align__(16) bf16_t BsL[128 * 32];
  const int nblk = N >> 7;
  const int bm = blockIdx.x / nblk;
  const int bn = blockIdx.x % nblk;
  const int tid  = threadIdx.x;
  const int wave = tid >> 6;
  const int lane = tid & 63;
  const int l15  = lane & 15;
  const int quad = lane >> 4;
  const int wm = wave >> 1, wn = wave & 1;

  const size_t aOff = (size_t)(bm * 128 + wave * 32 + (lane >> 2)) * K + (lane & 3) * 8;
  const size_t bOff = (size_t)(bn * 128 + wave * 32 + (lane >> 2)) * K + (lane & 3) * 8;
  const int ldsOff0 = (wave * 32) * 32;
  const int ldsOff1 = (wave * 32 + 16) * 32;

  f32x4 acc[4][4];
  #pragma unroll
  for (int i = 0; i < 4; i++)
    #pragma unroll
    for (int j = 0; j < 4; j++) acc[i][j] = (f32x4){0.f, 0.f, 0.f, 0.f};

  for (int kt = 0; kt < K; kt += 32) {
    async_copy16(Ah + aOff + kt, &AsH[ldsOff0]);
    async_copy16(Ah + aOff + kt + (size_t)16 * K, &AsH[ldsOff1]);
    async_copy16(Al + aOff + kt, &AsL[ldsOff0]);
    async_copy16(Al + aOff + kt + (size_t)16 * K, &AsL[ldsOff1]);
    async_copy16(Bh + bOff + kt, &BsH[ldsOff0]);
    async_copy16(Bh + bOff + kt + (size_t)16 * K, &BsH[ldsOff1]);
    async_copy16(Bl + bOff + kt, &BsL[ldsOff0]);
    async_copy16(Bl + bOff + kt + (size_t)16 * K, &BsL[ldsOff1]);
    __syncthreads();
    bf16x8 afH[4], afL[4], bfH[4], bfL[4];
    #pragma unroll
    for (int i = 0; i < 4; i++) {
      const int o = (wm * 64 + i * 16 + l15) * 32 + quad * 8;
      afH[i] = *(const bf16x8*)&AsH[o];
      afL[i] = *(const bf16x8*)&AsL[o];
    }
    #pragma unroll
    for (int j = 0; j < 4; j++) {
      const int o = (wn * 64 + j * 16 + l15) * 32 + quad * 8;
      bfH[j] = *(const bf16x8*)&BsH[o];
      bfL[j] = *(const bf16x8*)&BsL[o];
    }
    #pragma unroll
    for (int i = 0; i < 4; i++)
      #pragma unroll
      for (int j = 0; j < 4; j++) {
        acc[i][j] = __builtin_amdgcn_mfma_f32_16x16x32_bf16(afH[i], bfH[j], acc[i][j], 0, 0, 0);
        acc[i][j] = __builtin_amdgcn_mfma_f32_16x16x32_bf16(afH[i], bfL[j], acc[i][j], 0, 0, 0);
        acc[i][j] = __builtin_amdgcn_mfma_f32_16x16x32_bf16(afL[i], bfH[j], acc[i][j], 0, 0, 0);
      }
    __syncthreads();
  }

  const int gm0 = bm * 128 + wm * 64 + quad * 4;
  const int gn0 = bn * 128 + wn * 64 + l15;
  #pragma unroll
  for (int i = 0; i < 4; i++)
    #pragma unroll
    for (int j = 0; j < 4; j++) {
      const int gn = gn0 + j * 16;
      const float scale = (gn < 1024) ? QSCALE : 1.0f;
      #pragma unroll
      for (int r = 0; r < 4; r++) {
        const int gm = gm0 + i * 16 + r;
        bf16_t hi, lo;
        split_bf16(acc[i][j][r] * scale, hi, lo);
        out_hi[(size_t)gm * N + gn] = hi;
        out_lo[(size_t)gm * N + gn] = lo;
      }
    }
}

// ---------------- Flash attention v6: two-pass fixed-M softmax, 2 q-tiles/wave,
// pass-1 on 256-key chunks via LDS union (64 MFMA per barrier window).
// grid (16 qtiles, 16 heads, 4 batch), block 256 (4 waves x 32 queries).
// Scores arrive in log2 units (q prescaled by 8*log2e in QK-gemm epilogue).
// vT layout: [dim 0..1023][tok 0..8191]
__global__ __launch_bounds__(256) void attn_kernel(
    const bf16_t* __restrict__ qkH,  // [8192][2048] q' cols 0..1023, k cols 1024..2047
    const bf16_t* __restrict__ qkL,
    const bf16_t* __restrict__ vT,   // [1024][8192]
    bf16_t* __restrict__ o)          // [8192][1024]
{
  const int qt = blockIdx.x;
  const int h  = blockIdx.y;
  const int b  = blockIdx.z;
  const int wave = threadIdx.x >> 6;
  const int lane = threadIdx.x & 63;
  const int l15  = lane & 15;
  const int quad = lane >> 4;
  const int sw   = l15 & 7;
  const int qrowA = qt * 128 + wave * 32;
  const int qrowB = qrowA + 16;

  // 40 KB union: pass1 uses first 32 KB as Kbig[256][64];
  // pass2 uses KhL[64][64] | KlL[64][64] | VtL[64][64] | P[4][32][64].
  __shared__ __align__(16) bf16_t SMEM[20480];
  bf16_t* Kbig = SMEM;
  bf16_t* KhL  = SMEM;
  bf16_t* KlL  = SMEM + 4096;
  bf16_t* VtL  = SMEM + 8192;
  bf16_t* pw   = SMEM + 12288 + wave * 2048;

  const size_t tok0 = (size_t)b * 2048;
  const size_t qoffA = (tok0 + qrowA + l15) * 2048 + h * 64;
  const size_t qoffB = (tok0 + qrowB + l15) * 2048 + h * 64;
  const bf16x8 aA0H = *(const bf16x8*)(qkH + qoffA + quad * 8);
  const bf16x8 aA1H = *(const bf16x8*)(qkH + qoffA + 32 + quad * 8);
  const bf16x8 aA0L = *(const bf16x8*)(qkL + qoffA + quad * 8);
  const bf16x8 aA1L = *(const bf16x8*)(qkL + qoffA + 32 + quad * 8);
  const bf16x8 aB0H = *(const bf16x8*)(qkH + qoffB + quad * 8);
  const bf16x8 aB1H = *(const bf16x8*)(qkH + qoffB + 32 + quad * 8);
  const bf16x8 aB0L = *(const bf16x8*)(qkL + qoffB + quad * 8);
  const bf16x8 aB1L = *(const bf16x8*)(qkL + qoffB + 32 + quad * 8);

  const int kOff = 1024 + h * 64;
  const int rsub = lane >> 3;
  const int csw  = (lane & 7) ^ (rsub & 7);

  // ---------- pass 1: per-row max estimate from hi*hi scores, 256-key chunks.
  f32x4 mxA = (f32x4){-3.0e38f, -3.0e38f, -3.0e38f, -3.0e38f};
  f32x4 mxB = mxA;
  for (int kb = 0; kb < 2048; kb += 256) {
    #pragma unroll
    for (int j = 0; j < 8; j++) {
      const int row0 = wave * 64 + j * 8;
      async_copy16(qkH + (tok0 + kb + row0 + rsub) * 2048 + kOff + csw * 8,
                   &Kbig[row0 * 64]);
    }
    __syncthreads();
    #pragma unroll
    for (int t = 0; t < 16; t++) {
      const int base = (t * 16 + l15) * 64;
      const bf16x8 bh0 = *(const bf16x8*)&Kbig[base + ((quad) ^ sw) * 8];
      const bf16x8 bh1 = *(const bf16x8*)&Kbig[base + ((4 + quad) ^ sw) * 8];
      f32x4 accA = (f32x4){0.f, 0.f, 0.f, 0.f};
      f32x4 accB = accA;
      accA = __builtin_amdgcn_mfma_f32_16x16x32_bf16(aA0H, bh0, accA, 0, 0, 0);
      accA = __builtin_amdgcn_mfma_f32_16x16x32_bf16(aA1H, bh1, accA, 0, 0, 0);
      accB = __builtin_amdgcn_mfma_f32_16x16x32_bf16(aB0H, bh0, accB, 0, 0, 0);
      accB = __builtin_amdgcn_mfma_f32_16x16x32_bf16(aB1H, bh1, accB, 0, 0, 0);
      #pragma unroll
      for (int r = 0; r < 4; r++) {
        mxA[r] = fmaxf(mxA[r], accA[r]);
        mxB[r] = fmaxf(mxB[r], accB[r]);
      }
    }
    __syncthreads();
  }
  f32x4 negMA, negMB;
  #pragma unroll
  for (int r = 0; r < 4; r++) {
    float mA = mxA[r], mB = mxB[r];
    mA = fmaxf(mA, __shfl_xor(mA, 1)); mB = fmaxf(mB, __shfl_xor(mB, 1));
    mA = fmaxf(mA, __shfl_xor(mA, 2)); mB = fmaxf(mB, __shfl_xor(mB, 2));
    mA = fmaxf(mA, __shfl_xor(mA, 4)); mB = fmaxf(mB, __shfl_xor(mB, 4));
    mA = fmaxf(mA, __shfl_xor(mA, 8)); mB = fmaxf(mB, __shfl_xor(mB, 8));
    // +4 covers dropped lo-term error; overestimate cancels in l-divide.
    negMA[r] = -(mA + 4.0f);
    negMB[r] = -(mB + 4.0f);
  }

  // ---------- pass 2: p = exp2(score + negM); no rescaling, no per-chunk chains.
  f32x4 OfA[4], OfB[4];
  f32x4 lsumA = (f32x4){0.f, 0.f, 0.f, 0.f};
  f32x4 lsumB = lsumA;
  #pragma unroll
  for (int c = 0; c < 4; c++) { OfA[c] = lsumA; OfB[c] = lsumA; }

  for (int kb = 0; kb < 2048; kb += 64) {
    #pragma unroll
    for (int j = 0; j < 2; j++) {
      const int row0 = wave * 16 + j * 8;
      const size_t krow = tok0 + kb + row0 + rsub;
      async_copy16(qkH + krow * 2048 + kOff + csw * 8, &KhL[row0 * 64]);
      async_copy16(qkL + krow * 2048 + kOff + csw * 8, &KlL[row0 * 64]);
      async_copy16(vT + (size_t)(h * 64 + row0 + rsub) * 8192 + tok0 + kb + csw * 8,
                   &VtL[row0 * 64]);
    }
    __syncthreads();

    #pragma unroll
    for (int t = 0; t < 4; t++) {
      const int base = (t * 16 + l15) * 64;
      const bf16x8 bh0 = *(const bf16x8*)&KhL[base + ((quad) ^ sw) * 8];
      const bf16x8 bh1 = *(const bf16x8*)&KhL[base + ((4 + quad) ^ sw) * 8];
      const bf16x8 bl0 = *(const bf16x8*)&KlL[base + ((quad) ^ sw) * 8];
      const bf16x8 bl1 = *(const bf16x8*)&KlL[base + ((4 + quad) ^ sw) * 8];
      f32x4 accA = negMA;
      f32x4 accB = negMB;
      accA = __builtin_amdgcn_mfma_f32_16x16x32_bf16(aA0H, bh0, accA, 0, 0, 0);
      accA = __builtin_amdgcn_mfma_f32_16x16x32_bf16(aA1H, bh1, accA, 0, 0, 0);
      accA = __builtin_amdgcn_mfma_f32_16x16x32_bf16(aA0H, bl0, accA, 0, 0, 0);
      accA = __builtin_amdgcn_mfma_f32_16x16x32_bf16(aA1H, bl1, accA, 0, 0, 0);
      accA = __builtin_amdgcn_mfma_f32_16x16x32_bf16(aA0L, bh0, accA, 0, 0, 0);
      accA = __builtin_amdgcn_mfma_f32_16x16x32_bf16(aA1L, bh1, accA, 0, 0, 0);
      accB = __builtin_amdgcn_mfma_f32_16x16x32_bf16(aB0H, bh0, accB, 0, 0, 0);
      accB = __builtin_amdgcn_mfma_f32_16x16x32_bf16(aB1H, bh1, accB, 0, 0, 0);
      accB = __builtin_amdgcn_mfma_f32_16x16x32_bf16(aB0H, bl0, accB, 0, 0, 0);
      accB = __builtin_amdgcn_mfma_f32_16x16x32_bf16(aB1H, bl1, accB, 0, 0, 0);
      accB = __builtin_amdgcn_mfma_f32_16x16x32_bf16(aB0L, bh0, accB, 0, 0, 0);
      accB = __builtin_amdgcn_mfma_f32_16x16x32_bf16(aB1L, bh1, accB, 0, 0, 0);
      #pragma unroll
      for (int r = 0; r < 4; r++) {
        const float pA = __builtin_amdgcn_exp2f(accA[r]);
        const float pB = __builtin_amdgcn_exp2f(accB[r]);
        lsumA[r] += pA;
        lsumB[r] += pB;
        const int RA = quad * 4 + r;
        const int RB = 16 + RA;
        pw[RA * 64 + (((t * 2 + (l15 >> 3)) ^ (RA & 7)) * 8) + (l15 & 7)] =
            __float2bfloat16(pA);
        pw[RB * 64 + (((t * 2 + (l15 >> 3)) ^ (RB & 7)) * 8) + (l15 & 7)] =
            __float2bfloat16(pB);
      }
    }

    // PV (P round-trip is same-wave: no barrier needed)
    const bf16x8 paA0 = *(const bf16x8*)&pw[l15 * 64 + ((quad) ^ sw) * 8];
    const bf16x8 paA1 = *(const bf16x8*)&pw[l15 * 64 + ((4 + quad) ^ sw) * 8];
    const bf16x8 paB0 = *(const bf16x8*)&pw[(16 + l15) * 64 + ((quad) ^ sw) * 8];
    const bf16x8 paB1 = *(const bf16x8*)&pw[(16 + l15) * 64 + ((4 + quad) ^ sw) * 8];
    #pragma unroll
    for (int c = 0; c < 4; c++) {
      const int vb = (c * 16 + l15) * 64;
      const bf16x8 bv0 = *(const bf16x8*)&VtL[vb + ((quad) ^ sw) * 8];
      const bf16x8 bv1 = *(const bf16x8*)&VtL[vb + ((4 + quad) ^ sw) * 8];
      OfA[c] = __builtin_amdgcn_mfma_f32_16x16x32_bf16(paA0, bv0, OfA[c], 0, 0, 0);
      OfA[c] = __builtin_amdgcn_mfma_f32_16x16x32_bf16(paA1, bv1, OfA[c], 0, 0, 0);
      OfB[c] = __builtin_amdgcn_mfma_f32_16x16x32_bf16(paB0, bv0, OfB[c], 0, 0, 0);
      OfB[c] = __builtin_amdgcn_mfma_f32_16x16x32_bf16(paB1, bv1, OfB[c], 0, 0, 0);
    }
    __syncthreads();
  }

  float lrowA[4], lrowB[4];
  #pragma unroll
  for (int r = 0; r < 4; r++) {
    float cA = lsumA[r], cB = lsumB[r];
    cA += __shfl_xor(cA, 1); cB += __shfl_xor(cB, 1);
    cA += __shfl_xor(cA, 2); cB += __shfl_xor(cB, 2);
    cA += __shfl_xor(cA, 4); cB += __shfl_xor(cB, 4);
    cA += __shfl_xor(cA, 8); cB += __shfl_xor(cB, 8);
    lrowA[r] = cA; lrowB[r] = cB;
  }

  bf16_t* opA = o + (tok0 + qrowA) * 1024 + h * 64;
  bf16_t* opB = o + (tok0 + qrowB) * 1024 + h * 64;
  #pragma unroll
  for (int c = 0; c < 4; c++)
    #pragma unroll
    for (int r = 0; r < 4; r++) {
      opA[(size_t)(quad * 4 + r) * 1024 + c * 16 + l15] =
          __float2bfloat16(OfA[c][r] / lrowA[r]);
      opB[(size_t)(quad * 4 + r) * 1024 + c * 16 + l15] =
          __float2bfloat16(OfB[c][r] / lrowB[r]);
    }
}

extern "C" void kernel_launch(void* const* d_in, const int* in_sizes, int n_in,
                              void* d_out, int out_size, void* d_ws, size_t ws_size,
                              hipStream_t stream)
{
  (void)in_sizes; (void)n_in; (void)out_size; (void)ws_size;
  const float* x   = (const float*)d_in[0];
  const float* Wk  = (const float*)d_in[2];
  const float* Wq  = (const float*)d_in[3];
  const float* Wv  = (const float*)d_in[4];
  const float* Wfc = (const float*)d_in[5];
  const float* bfc = (const float*)d_in[6];
  const float* g1  = (const float*)d_in[7];
  const float* b1  = (const float*)d_in[8];
  const float* g2  = (const float*)d_in[9];
  const float* b2  = (const float*)d_in[10];
  const float* W1  = (const float*)d_in[11];
  const float* bf1 = (const float*)d_in[12];
  const float* W2  = (const float*)d_in[13];
  const float* bf2 = (const float*)d_in[14];
  float* out = (float*)d_out;

  // Workspace (aliased):
  //  @0   16MB: xl_hi -> oAtt
  //  @16  16MB: xl_lo -> vT (V^T [1024][8192]) -> xl2
  //  @32  64MB: qk_hi(32)+qk_lo(32) -> h1
  //  @112 32MB: x2
  //  @144 28MB: weights (Wqk hi/lo, WvT, WfcT, W1T, W2T)
  char* ws = (char*)d_ws;
  bf16_t* xl_hi  = (bf16_t*)(ws + (0ull   << 20));
  bf16_t* oAtt   = xl_hi;
  bf16_t* xl_lo  = (bf16_t*)(ws + (16ull  << 20));
  bf16_t* vT     = xl_lo;
  bf16_t* xl2    = xl_lo;
  bf16_t* qk_hi  = (bf16_t*)(ws + (32ull  << 20));
  bf16_t* qk_lo  = (bf16_t*)(ws + (64ull  << 20));
  bf16_t* h1     = qk_hi;
  float*  x2     = (float*) (ws + (112ull << 20));
  bf16_t* Wqk_hi = (bf16_t*)(ws + (144ull << 20));
  bf16_t* Wqk_lo = (bf16_t*)(ws + (148ull << 20));
  bf16_t* WvT    = (bf16_t*)(ws + (152ull << 20));
  bf16_t* WfcT   = (bf16_t*)(ws + (154ull << 20));
  bf16_t* W1T    = (bf16_t*)(ws + (156ull << 20));
  bf16_t* W2T    = (bf16_t*)(ws + (164ull << 20));

  const dim3 blk(256);

  // all weight transposes in one launch (input order: Wk=d_in[2], Wq=d_in[3])
  wtrans_all_kernel<<<12288, blk, 0, stream>>>(
      Wq, Wk, Wv, Wfc, W1, W2, Wqk_hi, Wqk_lo, WvT, WfcT, W1T, W2T);

  ln_kernel<true><<<8192, blk, 0, stream>>>(x, g1, b1, xl_hi, xl_lo);

  gemm_split_kernel<<<64 * 16, blk, 0, stream>>>(
      xl_hi, xl_lo, Wqk_hi, Wqk_lo, qk_hi, qk_lo, 8192, 2048, 1024);

  // V^T gemm: C[dim][tok] = WvT . xl_hi^T  (M=1024, N=8192)
  gemm_kernel<false, false, false, true><<<8 * 64, blk, 0, stream>>>(
      WvT, xl_hi, nullptr, nullptr, nullptr, vT, 1024, 8192, 1024);

  attn_kernel<<<dim3(16, 16, 4), blk, 0, stream>>>(qk_hi, qk_lo, vT, oAtt);

  gemm_kernel<true, false, true, false><<<64 * 8, blk, 0, stream>>>(
      oAtt, WfcT, bfc, x, x2, nullptr, 8192, 1024, 1024);

  ln_kernel<false><<<8192, blk, 0, stream>>>(x2, g2, b2, xl2, nullptr);

  gemm_kernel<true, true, false, true><<<64 * 32, blk, 0, stream>>>(
      xl2, W1T, bf1, nullptr, nullptr, h1, 8192, 4096, 1024);

  gemm_kernel<true, false, true, false><<<64 * 8, blk, 0, stream>>>(
      h1, W2T, bf2, x2, out, nullptr, 8192, 1024, 4096);
}

// Round 7
// 663.361 us; speedup vs baseline: 1.8378x; 1.0890x over previous
//
#include <hip/hip_runtime.h>
#include <hip/hip_bf16.h>
#include <math.h>

// EncoderLayer for MI355X (gfx950).
// Numerics: scores = q.k * sqrt(C)=8 (reference quirk) => logits ~N(0,64^2),
// near-one-hot softmax => q,k computed/consumed in SPLIT bf16 (hi+lo ~= fp32).
// Attention: TWO-PASS softmax with fixed per-row M (pass1 hi*hi estimate + 4;
// fixed M cancels in the l-divide). 8*log2e folded into q in QK-gemm epilogue.
// R7: plain GEMM -> BK=64 (32 MFMA per barrier, halved barrier count) with
// XOR-swizzled LDS (slot = chunk ^ (row&7), 2 lanes/bank = free per m136);
// split GEMM gets pair-row swizzle (slot = chunk ^ ((row>>1)&3), 8-way -> 2-way).

typedef __hip_bfloat16 bf16_t;
typedef __bf16 bf16x8 __attribute__((ext_vector_type(8)));
typedef float f32x4 __attribute__((ext_vector_type(4)));

#define LN_EPS 1e-5f
#define QSCALE 11.541560327111707f  // 8 * log2(e)

__device__ __forceinline__ void async_copy16(const bf16_t* g, bf16_t* l) {
  __builtin_amdgcn_global_load_lds(
      (const __attribute__((address_space(1))) void*)g,
      (__attribute__((address_space(3))) void*)l,
      16 /*bytes*/, 0 /*offset*/, 0 /*aux*/);
}

__device__ __forceinline__ void split_bf16(float v, bf16_t& hi, bf16_t& lo) {
  hi = __float2bfloat16(v);
  lo = __float2bfloat16(v - __bfloat162float(hi));
}

// ---------------- LayerNorm: fp32 in -> bf16 out (one block per row of 1024)
template<bool SPLIT>
__global__ __launch_bounds__(256) void ln_kernel(
    const float* __restrict__ x, const float* __restrict__ g,
    const float* __restrict__ b, bf16_t* __restrict__ out_hi,
    bf16_t* __restrict__ out_lo)
{
  const int row = blockIdx.x;
  const int tid = threadIdx.x;
  const float4 v = *(const float4*)(x + (size_t)row * 1024 + tid * 4);
  float s  = v.x + v.y + v.z + v.w;
  float ss = v.x * v.x + v.y * v.y + v.z * v.z + v.w * v.w;
  for (int off = 32; off > 0; off >>= 1) {
    s  += __shfl_down(s, off);
    ss += __shfl_down(ss, off);
  }
  __shared__ float sb[4], ssb[4];
  const int wave = tid >> 6, lane = tid & 63;
  if (lane == 0) { sb[wave] = s; ssb[wave] = ss; }
  __syncthreads();
  const float tot  = sb[0] + sb[1] + sb[2] + sb[3];
  const float tots = ssb[0] + ssb[1] + ssb[2] + ssb[3];
  const float mu   = tot * (1.0f / 1024.0f);
  const float var  = tots * (1.0f / 1024.0f) - mu * mu;
  const float rstd = rsqrtf(var + LN_EPS);
  const float4 gv = *(const float4*)(g + tid * 4);
  const float4 bv = *(const float4*)(b + tid * 4);
  float y[4] = {(v.x - mu) * rstd * gv.x + bv.x,
                (v.y - mu) * rstd * gv.y + bv.y,
                (v.z - mu) * rstd * gv.z + bv.z,
                (v.w - mu) * rstd * gv.w + bv.w};
  bf16_t hi[4] __attribute__((aligned(8)));
  bf16_t lo[4] __attribute__((aligned(8)));
  #pragma unroll
  for (int i = 0; i < 4; i++) split_bf16(y[i], hi[i], lo[i]);
  uint2 ph, pl;
  __builtin_memcpy(&ph, hi, 8);
  *(uint2*)(out_hi + (size_t)row * 1024 + tid * 4) = ph;
  if (SPLIT) {
    __builtin_memcpy(&pl, lo, 8);
    *(uint2*)(out_lo + (size_t)row * 1024 + tid * 4) = pl;
  }
}

// ---------------- Batched weight transpose + cast (all 6 weights, one launch)
__global__ __launch_bounds__(256) void wtrans_all_kernel(
    const float* __restrict__ Wq, const float* __restrict__ Wk,
    const float* __restrict__ Wv, const float* __restrict__ Wfc,
    const float* __restrict__ W1, const float* __restrict__ W2,
    bf16_t* __restrict__ WqkH, bf16_t* __restrict__ WqkL,
    bf16_t* __restrict__ WvT, bf16_t* __restrict__ WfcT,
    bf16_t* __restrict__ W1T, bf16_t* __restrict__ W2T)
{
  const int id = blockIdx.x;
  const float* W; bf16_t* DH; bf16_t* DL = nullptr;
  int K, N, n0, k0;
  if (id < 4096) {
    K = 1024; N = 1024;
    const int local = id & 1023;
    n0 = (local & 31) * 32; k0 = (local >> 5) * 32;
    if (id < 1024)      { W = Wq;  DH = WqkH;                 DL = WqkL; }
    else if (id < 2048) { W = Wk;  DH = WqkH + 1024 * 1024;   DL = WqkL + 1024 * 1024; }
    else if (id < 3072) { W = Wv;  DH = WvT; }
    else                { W = Wfc; DH = WfcT; }
  } else if (id < 8192) {
    const int local = id - 4096;
    K = 1024; N = 4096; W = W1; DH = W1T;
    n0 = (local & 127) * 32; k0 = (local >> 7) * 32;
  } else {
    const int local = id - 8192;
    K = 4096; N = 1024; W = W2; DH = W2T;
    n0 = (local & 31) * 32; k0 = (local >> 5) * 32;
  }
  __shared__ float t[32][33];
  const int tx = threadIdx.x & 31, ty = threadIdx.x >> 5;
  #pragma unroll
  for (int r = ty; r < 32; r += 8)
    t[r][tx] = W[(size_t)(k0 + r) * N + n0 + tx];
  __syncthreads();
  #pragma unroll
  for (int r = ty; r < 32; r += 8) {
    const float v = t[tx][r];
    bf16_t hi, lo;
    split_bf16(v, hi, lo);
    DH[(size_t)(n0 + r) * K + k0 + tx] = hi;
    if (DL) DL[(size_t)(n0 + r) * K + k0 + tx] = lo;
  }
}

// ---------------- GEMM (BK=64, swizzled): C = A(MxK) * BT(NxK)^T [+bias][+resid][relu]
// 128x128 tile, 4 waves (2x2), each wave 64x64 via 4x4 mfma 16x16x32 over 2 k-subtiles.
// LDS row r slot s (16B chunks) holds global chunk s ^ (r&7): fragment reads are
// 2 lanes/bank (free); staging global_load_lds is lane-contiguous by construction.
template<bool BIAS, bool RELU, bool RESID, bool OUTBF>
__global__ __launch_bounds__(256) void gemm_kernel(
    const bf16_t* __restrict__ A, const bf16_t* __restrict__ BT,
    const float* __restrict__ bias, const float* __restrict__ resid,
    float* __restrict__ outF, bf16_t* __restrict__ outB,
    int M, int N, int K)
{
  __shared__ __align__(16) bf16_t As[128 * 64];
  __shared__ __align__(16) bf16_t Bs[128 * 64];
  const int nblk = N >> 7;
  const int bm = blockIdx.x / nblk;
  const int bn = blockIdx.x % nblk;
  const int tid  = threadIdx.x;
  const int wave = tid >> 6;
  const int lane = tid & 63;
  const int l15  = lane & 15;
  const int quad = lane >> 4;
  const int wm = wave >> 1, wn = wave & 1;

  // staging: copy j covers rows wave*32 + j*8 .. +8; lane i -> row +(i>>3),
  // LDS slot (i&7) => global chunk (i&7)^((i>>3)&7)  [slot s = chunk s^(r&7)]
  const int srow = lane >> 3;
  const int schunk = (lane & 7) ^ srow;
  const bf16_t* aG = A  + (size_t)(bm * 128 + wave * 32 + srow) * K + schunk * 8;
  const bf16_t* bG = BT + (size_t)(bn * 128 + wave * 32 + srow) * K + schunk * 8;

  f32x4 acc[4][4];
  #pragma unroll
  for (int i = 0; i < 4; i++)
    #pragma unroll
    for (int j = 0; j < 4; j++) acc[i][j] = (f32x4){0.f, 0.f, 0.f, 0.f};

  const int rsw = l15 & 7;  // fragment-row swizzle key (R&7 = l15&7)

  for (int kt = 0; kt < K; kt += 64) {
    #pragma unroll
    for (int j = 0; j < 4; j++) {
      async_copy16(aG + kt + (size_t)(j * 8) * K, &As[(wave * 32 + j * 8) * 64]);
      async_copy16(bG + kt + (size_t)(j * 8) * K, &Bs[(wave * 32 + j * 8) * 64]);
    }
    __syncthreads();
    #pragma unroll
    for (int ko = 0; ko < 2; ko++) {
      bf16x8 af[4], bfr[4];
      #pragma unroll
      for (int i = 0; i < 4; i++)
        af[i]  = *(const bf16x8*)&As[(wm * 64 + i * 16 + l15) * 64 +
                                     (((ko * 4 + quad) ^ rsw) * 8)];
      #pragma unroll
      for (int j = 0; j < 4; j++)
        bfr[j] = *(const bf16x8*)&Bs[(wn * 64 + j * 16 + l15) * 64 +
                                     (((ko * 4 + quad) ^ rsw) * 8)];
      #pragma unroll
      for (int i = 0; i < 4; i++)
        #pragma unroll
        for (int j = 0; j < 4; j++)
          acc[i][j] = __builtin_amdgcn_mfma_f32_16x16x32_bf16(af[i], bfr[j], acc[i][j], 0, 0, 0);
    }
    __syncthreads();
  }

  const int gm0 = bm * 128 + wm * 64 + quad * 4;
  const int gn0 = bn * 128 + wn * 64 + l15;
  #pragma unroll
  for (int i = 0; i < 4; i++) {
    #pragma unroll
    for (int j = 0; j < 4; j++) {
      const int gn = gn0 + j * 16;
      const float bz = BIAS ? bias[gn] : 0.0f;
      #pragma unroll
      for (int r = 0; r < 4; r++) {
        const int gm = gm0 + i * 16 + r;
        float v = acc[i][j][r] + bz;
        if (RESID) v += resid[(size_t)gm * N + gn];
        if (RELU)  v = fmaxf(v, 0.0f);
        if (OUTBF) outB[(size_t)gm * N + gn] = __float2bfloat16(v);
        else       outF[(size_t)gm * N + gn] = v;
      }
    }
  }
}

// ---------------- Split-precision GEMM for q,k (BK=32, pair-row swizzle).
// LDS row r slot s holds global chunk s ^ ((r>>1)&3): reads 2 lanes/bank.
// Epilogue scales q columns (gn<1024) by 8*log2e in fp32 BEFORE re-splitting.
__global__ __launch_bounds__(256) void gemm_split_kernel(
    const bf16_t* __restrict__ Ah, const bf16_t* __restrict__ Al,
    const bf16_t* __restrict__ Bh, const bf16_t* __restrict__ Bl,
    bf16_t* __restrict__ out_hi, bf16_t* __restrict__ out_lo,
    int M, int N, int K)
{
  __shared__ __align__(16) bf16_t AsH[128 * 32];
  __shared__ __align__(16) bf16_t AsL[128 * 32];
  __shared__ __align__(16) bf16_t BsH[128 * 32];
  __shared__ __align__(16) bf16_t BsL[128 * 32];
  const int nblk = N >> 7;
  const int bm = blockIdx.x / nblk;
  const int bn = blockIdx.x % nblk;
  const int tid  = threadIdx.x;
  const int wave = tid >> 6;
  const int lane = tid & 63;
  const int l15  = lane & 15;
  const int quad = lane >> 4;
  const int wm = wave >> 1, wn = wave & 1;

  // staging: lane i -> row (i>>2), LDS slot (i&3) => global chunk (i&3)^((i>>3)&3)
  const int srow = lane >> 2;
  const int schunk = (lane & 3) ^ ((lane >> 3) & 3);
  const size_t aOff = (size_t)(bm * 128 + wave * 32 + srow) * K + schunk * 8;
  const size_t bOff = (size_t)(bn * 128 + wave * 32 + srow) * K + schunk * 8;
  const int ldsOff0 = (wave * 32) * 32;
  const int ldsOff1 = (wave * 32 + 16) * 32;

  f32x4 acc[4][4];
  #pragma unroll
  for (int i = 0; i < 4; i++)
    #pragma unroll
    for (int j = 0; j < 4; j++) acc[i][j] = (f32x4){0.f, 0.f, 0.f, 0.f};

  const int rsw = (l15 >> 1) & 3;  // (R>>1)&3 for fragment rows

  for (int kt = 0; kt < K; kt += 32) {
    async_copy16(Ah + aOff + kt, &AsH[ldsOff0]);
    async_copy16(Ah + aOff + kt + (size_t)16 * K, &AsH[ldsOff1]);
    async_copy16(Al + aOff + kt, &AsL[ldsOff0]);
    async_copy16(Al + aOff + kt + (size_t)16 * K, &AsL[ldsOff1]);
    async_copy16(Bh + bOff + kt, &BsH[ldsOff0]);
    async_copy16(Bh + bOff + kt + (size_t)16 * K, &BsH[ldsOff1]);
    async_copy16(Bl + bOff + kt, &BsL[ldsOff0]);
    async_copy16(Bl + bOff + kt + (size_t)16 * K, &BsL[ldsOff1]);
    __syncthreads();
    bf16x8 afH[4], afL[4], bfH[4], bfL[4];
    #pragma unroll
    for (int i = 0; i < 4; i++) {
      const int o = (wm * 64 + i * 16 + l15) * 32 + ((quad ^ rsw) * 8);
      afH[i] = *(const bf16x8*)&AsH[o];
      afL[i] = *(const bf16x8*)&AsL[o];
    }
    #pragma unroll
    for (int j = 0; j < 4; j++) {
      const int o = (wn * 64 + j * 16 + l15) * 32 + ((quad ^ rsw) * 8);
      bfH[j] = *(const bf16x8*)&BsH[o];
      bfL[j] = *(const bf16x8*)&BsL[o];
    }
    #pragma unroll
    for (int i = 0; i < 4; i++)
      #pragma unroll
      for (int j = 0; j < 4; j++) {
        acc[i][j] = __builtin_amdgcn_mfma_f32_16x16x32_bf16(afH[i], bfH[j], acc[i][j], 0, 0, 0);
        acc[i][j] = __builtin_amdgcn_mfma_f32_16x16x32_bf16(afH[i], bfL[j], acc[i][j], 0, 0, 0);
        acc[i][j] = __builtin_amdgcn_mfma_f32_16x16x32_bf16(afL[i], bfH[j], acc[i][j], 0, 0, 0);
      }
    __syncthreads();
  }

  const int gm0 = bm * 128 + wm * 64 + quad * 4;
  const int gn0 = bn * 128 + wn * 64 + l15;
  #pragma unroll
  for (int i = 0; i < 4; i++)
    #pragma unroll
    for (int j = 0; j < 4; j++) {
      const int gn = gn0 + j * 16;
      const float scale = (gn < 1024) ? QSCALE : 1.0f;
      #pragma unroll
      for (int r = 0; r < 4; r++) {
        const int gm = gm0 + i * 16 + r;
        bf16_t hi, lo;
        split_bf16(acc[i][j][r] * scale, hi, lo);
        out_hi[(size_t)gm * N + gn] = hi;
        out_lo[(size_t)gm * N + gn] = lo;
      }
    }
}

// ---------------- Flash attention v6 (unchanged from R6): two-pass fixed-M,
// 2 q-tiles/wave, pass-1 on 256-key chunks via LDS union.
__global__ __launch_bounds__(256) void attn_kernel(
    const bf16_t* __restrict__ qkH,  // [8192][2048] q' cols 0..1023, k cols 1024..2047
    const bf16_t* __restrict__ qkL,
    const bf16_t* __restrict__ vT,   // [1024][8192]
    bf16_t* __restrict__ o)          // [8192][1024]
{
  const int qt = blockIdx.x;
  const int h  = blockIdx.y;
  const int b  = blockIdx.z;
  const int wave = threadIdx.x >> 6;
  const int lane = threadIdx.x & 63;
  const int l15  = lane & 15;
  const int quad = lane >> 4;
  const int sw   = l15 & 7;
  const int qrowA = qt * 128 + wave * 32;
  const int qrowB = qrowA + 16;

  __shared__ __align__(16) bf16_t SMEM[20480];
  bf16_t* Kbig = SMEM;
  bf16_t* KhL  = SMEM;
  bf16_t* KlL  = SMEM + 4096;
  bf16_t* VtL  = SMEM + 8192;
  bf16_t* pw   = SMEM + 12288 + wave * 2048;

  const size_t tok0 = (size_t)b * 2048;
  const size_t qoffA = (tok0 + qrowA + l15) * 2048 + h * 64;
  const size_t qoffB = (tok0 + qrowB + l15) * 2048 + h * 64;
  const bf16x8 aA0H = *(const bf16x8*)(qkH + qoffA + quad * 8);
  const bf16x8 aA1H = *(const bf16x8*)(qkH + qoffA + 32 + quad * 8);
  const bf16x8 aA0L = *(const bf16x8*)(qkL + qoffA + quad * 8);
  const bf16x8 aA1L = *(const bf16x8*)(qkL + qoffA + 32 + quad * 8);
  const bf16x8 aB0H = *(const bf16x8*)(qkH + qoffB + quad * 8);
  const bf16x8 aB1H = *(const bf16x8*)(qkH + qoffB + 32 + quad * 8);
  const bf16x8 aB0L = *(const bf16x8*)(qkL + qoffB + quad * 8);
  const bf16x8 aB1L = *(const bf16x8*)(qkL + qoffB + 32 + quad * 8);

  const int kOff = 1024 + h * 64;
  const int rsub = lane >> 3;
  const int csw  = (lane & 7) ^ (rsub & 7);

  // pass 1: hi*hi max estimate, 256-key chunks
  f32x4 mxA = (f32x4){-3.0e38f, -3.0e38f, -3.0e38f, -3.0e38f};
  f32x4 mxB = mxA;
  for (int kb = 0; kb < 2048; kb += 256) {
    #pragma unroll
    for (int j = 0; j < 8; j++) {
      const int row0 = wave * 64 + j * 8;
      async_copy16(qkH + (tok0 + kb + row0 + rsub) * 2048 + kOff + csw * 8,
                   &Kbig[row0 * 64]);
    }
    __syncthreads();
    #pragma unroll
    for (int t = 0; t < 16; t++) {
      const int base = (t * 16 + l15) * 64;
      const bf16x8 bh0 = *(const bf16x8*)&Kbig[base + ((quad) ^ sw) * 8];
      const bf16x8 bh1 = *(const bf16x8*)&Kbig[base + ((4 + quad) ^ sw) * 8];
      f32x4 accA = (f32x4){0.f, 0.f, 0.f, 0.f};
      f32x4 accB = accA;
      accA = __builtin_amdgcn_mfma_f32_16x16x32_bf16(aA0H, bh0, accA, 0, 0, 0);
      accA = __builtin_amdgcn_mfma_f32_16x16x32_bf16(aA1H, bh1, accA, 0, 0, 0);
      accB = __builtin_amdgcn_mfma_f32_16x16x32_bf16(aB0H, bh0, accB, 0, 0, 0);
      accB = __builtin_amdgcn_mfma_f32_16x16x32_bf16(aB1H, bh1, accB, 0, 0, 0);
      #pragma unroll
      for (int r = 0; r < 4; r++) {
        mxA[r] = fmaxf(mxA[r], accA[r]);
        mxB[r] = fmaxf(mxB[r], accB[r]);
      }
    }
    __syncthreads();
  }
  f32x4 negMA, negMB;
  #pragma unroll
  for (int r = 0; r < 4; r++) {
    float mA = mxA[r], mB = mxB[r];
    mA = fmaxf(mA, __shfl_xor(mA, 1)); mB = fmaxf(mB, __shfl_xor(mB, 1));
    mA = fmaxf(mA, __shfl_xor(mA, 2)); mB = fmaxf(mB, __shfl_xor(mB, 2));
    mA = fmaxf(mA, __shfl_xor(mA, 4)); mB = fmaxf(mB, __shfl_xor(mB, 4));
    mA = fmaxf(mA, __shfl_xor(mA, 8)); mB = fmaxf(mB, __shfl_xor(mB, 8));
    negMA[r] = -(mA + 4.0f);
    negMB[r] = -(mB + 4.0f);
  }

  // pass 2
  f32x4 OfA[4], OfB[4];
  f32x4 lsumA = (f32x4){0.f, 0.f, 0.f, 0.f};
  f32x4 lsumB = lsumA;
  #pragma unroll
  for (int c = 0; c < 4; c++) { OfA[c] = lsumA; OfB[c] = lsumA; }

  for (int kb = 0; kb < 2048; kb += 64) {
    #pragma unroll
    for (int j = 0; j < 2; j++) {
      const int row0 = wave * 16 + j * 8;
      const size_t krow = tok0 + kb + row0 + rsub;
      async_copy16(qkH + krow * 2048 + kOff + csw * 8, &KhL[row0 * 64]);
      async_copy16(qkL + krow * 2048 + kOff + csw * 8, &KlL[row0 * 64]);
      async_copy16(vT + (size_t)(h * 64 + row0 + rsub) * 8192 + tok0 + kb + csw * 8,
                   &VtL[row0 * 64]);
    }
    __syncthreads();

    #pragma unroll
    for (int t = 0; t < 4; t++) {
      const int base = (t * 16 + l15) * 64;
      const bf16x8 bh0 = *(const bf16x8*)&KhL[base + ((quad) ^ sw) * 8];
      const bf16x8 bh1 = *(const bf16x8*)&KhL[base + ((4 + quad) ^ sw) * 8];
      const bf16x8 bl0 = *(const bf16x8*)&KlL[base + ((quad) ^ sw) * 8];
      const bf16x8 bl1 = *(const bf16x8*)&KlL[base + ((4 + quad) ^ sw) * 8];
      f32x4 accA = negMA;
      f32x4 accB = negMB;
      accA = __builtin_amdgcn_mfma_f32_16x16x32_bf16(aA0H, bh0, accA, 0, 0, 0);
      accA = __builtin_amdgcn_mfma_f32_16x16x32_bf16(aA1H, bh1, accA, 0, 0, 0);
      accA = __builtin_amdgcn_mfma_f32_16x16x32_bf16(aA0H, bl0, accA, 0, 0, 0);
      accA = __builtin_amdgcn_mfma_f32_16x16x32_bf16(aA1H, bl1, accA, 0, 0, 0);
      accA = __builtin_amdgcn_mfma_f32_16x16x32_bf16(aA0L, bh0, accA, 0, 0, 0);
      accA = __builtin_amdgcn_mfma_f32_16x16x32_bf16(aA1L, bh1, accA, 0, 0, 0);
      accB = __builtin_amdgcn_mfma_f32_16x16x32_bf16(aB0H, bh0, accB, 0, 0, 0);
      accB = __builtin_amdgcn_mfma_f32_16x16x32_bf16(aB1H, bh1, accB, 0, 0, 0);
      accB = __builtin_amdgcn_mfma_f32_16x16x32_bf16(aB0H, bl0, accB, 0, 0, 0);
      accB = __builtin_amdgcn_mfma_f32_16x16x32_bf16(aB1H, bl1, accB, 0, 0, 0);
      accB = __builtin_amdgcn_mfma_f32_16x16x32_bf16(aB0L, bh0, accB, 0, 0, 0);
      accB = __builtin_amdgcn_mfma_f32_16x16x32_bf16(aB1L, bh1, accB, 0, 0, 0);
      #pragma unroll
      for (int r = 0; r < 4; r++) {
        const float pA = __builtin_amdgcn_exp2f(accA[r]);
        const float pB = __builtin_amdgcn_exp2f(accB[r]);
        lsumA[r] += pA;
        lsumB[r] += pB;
        const int RA = quad * 4 + r;
        const int RB = 16 + RA;
        pw[RA * 64 + (((t * 2 + (l15 >> 3)) ^ (RA & 7)) * 8) + (l15 & 7)] =
            __float2bfloat16(pA);
        pw[RB * 64 + (((t * 2 + (l15 >> 3)) ^ (RB & 7)) * 8) + (l15 & 7)] =
            __float2bfloat16(pB);
      }
    }

    const bf16x8 paA0 = *(const bf16x8*)&pw[l15 * 64 + ((quad) ^ sw) * 8];
    const bf16x8 paA1 = *(const bf16x8*)&pw[l15 * 64 + ((4 + quad) ^ sw) * 8];
    const bf16x8 paB0 = *(const bf16x8*)&pw[(16 + l15) * 64 + ((quad) ^ sw) * 8];
    const bf16x8 paB1 = *(const bf16x8*)&pw[(16 + l15) * 64 + ((4 + quad) ^ sw) * 8];
    #pragma unroll
    for (int c = 0; c < 4; c++) {
      const int vb = (c * 16 + l15) * 64;
      const bf16x8 bv0 = *(const bf16x8*)&VtL[vb + ((quad) ^ sw) * 8];
      const bf16x8 bv1 = *(const bf16x8*)&VtL[vb + ((4 + quad) ^ sw) * 8];
      OfA[c] = __builtin_amdgcn_mfma_f32_16x16x32_bf16(paA0, bv0, OfA[c], 0, 0, 0);
      OfA[c] = __builtin_amdgcn_mfma_f32_16x16x32_bf16(paA1, bv1, OfA[c], 0, 0, 0);
      OfB[c] = __builtin_amdgcn_mfma_f32_16x16x32_bf16(paB0, bv0, OfB[c], 0, 0, 0);
      OfB[c] = __builtin_amdgcn_mfma_f32_16x16x32_bf16(paB1, bv1, OfB[c], 0, 0, 0);
    }
    __syncthreads();
  }

  float lrowA[4], lrowB[4];
  #pragma unroll
  for (int r = 0; r < 4; r++) {
    float cA = lsumA[r], cB = lsumB[r];
    cA += __shfl_xor(cA, 1); cB += __shfl_xor(cB, 1);
    cA += __shfl_xor(cA, 2); cB += __shfl_xor(cB, 2);
    cA += __shfl_xor(cA, 4); cB += __shfl_xor(cB, 4);
    cA += __shfl_xor(cA, 8); cB += __shfl_xor(cB, 8);
    lrowA[r] = cA; lrowB[r] = cB;
  }

  bf16_t* opA = o + (tok0 + qrowA) * 1024 + h * 64;
  bf16_t* opB = o + (tok0 + qrowB) * 1024 + h * 64;
  #pragma unroll
  for (int c = 0; c < 4; c++)
    #pragma unroll
    for (int r = 0; r < 4; r++) {
      opA[(size_t)(quad * 4 + r) * 1024 + c * 16 + l15] =
          __float2bfloat16(OfA[c][r] / lrowA[r]);
      opB[(size_t)(quad * 4 + r) * 1024 + c * 16 + l15] =
          __float2bfloat16(OfB[c][r] / lrowB[r]);
    }
}

extern "C" void kernel_launch(void* const* d_in, const int* in_sizes, int n_in,
                              void* d_out, int out_size, void* d_ws, size_t ws_size,
                              hipStream_t stream)
{
  (void)in_sizes; (void)n_in; (void)out_size; (void)ws_size;
  const float* x   = (const float*)d_in[0];
  const float* Wk  = (const float*)d_in[2];
  const float* Wq  = (const float*)d_in[3];
  const float* Wv  = (const float*)d_in[4];
  const float* Wfc = (const float*)d_in[5];
  const float* bfc = (const float*)d_in[6];
  const float* g1  = (const float*)d_in[7];
  const float* b1  = (const float*)d_in[8];
  const float* g2  = (const float*)d_in[9];
  const float* b2  = (const float*)d_in[10];
  const float* W1  = (const float*)d_in[11];
  const float* bf1 = (const float*)d_in[12];
  const float* W2  = (const float*)d_in[13];
  const float* bf2 = (const float*)d_in[14];
  float* out = (float*)d_out;

  char* ws = (char*)d_ws;
  bf16_t* xl_hi  = (bf16_t*)(ws + (0ull   << 20));
  bf16_t* oAtt   = xl_hi;
  bf16_t* xl_lo  = (bf16_t*)(ws + (16ull  << 20));
  bf16_t* vT     = xl_lo;
  bf16_t* xl2    = xl_lo;
  bf16_t* qk_hi  = (bf16_t*)(ws + (32ull  << 20));
  bf16_t* qk_lo  = (bf16_t*)(ws + (64ull  << 20));
  bf16_t* h1     = qk_hi;
  float*  x2     = (float*) (ws + (112ull << 20));
  bf16_t* Wqk_hi = (bf16_t*)(ws + (144ull << 20));
  bf16_t* Wqk_lo = (bf16_t*)(ws + (148ull << 20));
  bf16_t* WvT    = (bf16_t*)(ws + (152ull << 20));
  bf16_t* WfcT   = (bf16_t*)(ws + (154ull << 20));
  bf16_t* W1T    = (bf16_t*)(ws + (156ull << 20));
  bf16_t* W2T    = (bf16_t*)(ws + (164ull << 20));

  const dim3 blk(256);

  wtrans_all_kernel<<<12288, blk, 0, stream>>>(
      Wq, Wk, Wv, Wfc, W1, W2, Wqk_hi, Wqk_lo, WvT, WfcT, W1T, W2T);

  ln_kernel<true><<<8192, blk, 0, stream>>>(x, g1, b1, xl_hi, xl_lo);

  gemm_split_kernel<<<64 * 16, blk, 0, stream>>>(
      xl_hi, xl_lo, Wqk_hi, Wqk_lo, qk_hi, qk_lo, 8192, 2048, 1024);

  // V^T gemm: C[dim][tok] = WvT . xl_hi^T  (M=1024, N=8192)
  gemm_kernel<false, false, false, true><<<8 * 64, blk, 0, stream>>>(
      WvT, xl_hi, nullptr, nullptr, nullptr, vT, 1024, 8192, 1024);

  attn_kernel<<<dim3(16, 16, 4), blk, 0, stream>>>(qk_hi, qk_lo, vT, oAtt);

  gemm_kernel<true, false, true, false><<<64 * 8, blk, 0, stream>>>(
      oAtt, WfcT, bfc, x, x2, nullptr, 8192, 1024, 1024);

  ln_kernel<false><<<8192, blk, 0, stream>>>(x2, g2, b2, xl2, nullptr);

  gemm_kernel<true, true, false, true><<<64 * 32, blk, 0, stream>>>(
      xl2, W1T, bf1, nullptr, nullptr, h1, 8192, 4096, 1024);

  gemm_kernel<true, false, true, false><<<64 * 8, blk, 0, stream>>>(
      h1, W2T, bf2, x2, out, nullptr, 8192, 1024, 4096);
}